// Round 2
// baseline (1073.018 us; speedup 1.0000x reference)
//
#include <hip/hip_runtime.h>
#include <cstdint>

#define NN 100000
#define EE 1600000
#define GG 64
#define FIN 128
#define HC 256      // H*C for layer 1
#define NC 10

static __device__ __forceinline__ float lrelu(float x) { return x > 0.f ? x : 0.2f * x; }

// ---------------- utility ----------------
__global__ void k_zero(unsigned int* __restrict__ p, int n) {
  int i = blockIdx.x * 256 + threadIdx.x;
  if (i < n) p[i] = 0u;
}

// ---------------- GEMM1: h1 = x @ W1  (fp32 in, fp32 out) ----------------
// tile 64 rows x 256 cols, K=128, k-chunk 8. thread: 4 rows x 16 cols (4 col groups of 4)
__global__ __launch_bounds__(256) void k_gemm1(const float* __restrict__ x,
                                               const float* __restrict__ W1,
                                               float* __restrict__ h1) {
  __shared__ float As[8][64];
  __shared__ float Bs[8][256];
  const int t = threadIdx.x;
  const int m0 = blockIdx.x * 64;
  const int tx = t & 15;
  const int ty = t >> 4;
  float4 acc[4][4];
#pragma unroll
  for (int j = 0; j < 4; ++j)
#pragma unroll
    for (int r = 0; r < 4; ++r) acc[j][r] = make_float4(0.f, 0.f, 0.f, 0.f);

  for (int k0 = 0; k0 < FIN; k0 += 8) {
    __syncthreads();
    if (t < 128) {
      int m = t >> 1;
      int kk = (t & 1) * 4;
      int row = m0 + m; if (row >= NN) row = NN - 1;
      const float4 xv = *(const float4*)(x + row * FIN + k0 + kk);
      As[kk + 0][m] = xv.x; As[kk + 1][m] = xv.y;
      As[kk + 2][m] = xv.z; As[kk + 3][m] = xv.w;
    }
#pragma unroll
    for (int i = 0; i < 8; ++i) Bs[i][t] = W1[(k0 + i) * HC + t];
    __syncthreads();
#pragma unroll
    for (int k = 0; k < 8; ++k) {
      const float4 a4 = *(const float4*)&As[k][ty * 4];
      const float ar[4] = {a4.x, a4.y, a4.z, a4.w};
#pragma unroll
      for (int j = 0; j < 4; ++j) {
        const float4 b4 = *(const float4*)&Bs[k][tx * 4 + 64 * j];
#pragma unroll
        for (int r = 0; r < 4; ++r) {
          acc[j][r].x += ar[r] * b4.x; acc[j][r].y += ar[r] * b4.y;
          acc[j][r].z += ar[r] * b4.z; acc[j][r].w += ar[r] * b4.w;
        }
      }
    }
  }
#pragma unroll
  for (int r = 0; r < 4; ++r) {
    int row = m0 + ty * 4 + r;
    if (row < NN) {
#pragma unroll
      for (int j = 0; j < 4; ++j) {
        *(float4*)(h1 + (size_t)row * HC + tx * 4 + 64 * j) = acc[j][r];
      }
    }
  }
}

// ---------------- scores1: a_s[n,h], a_d[n,h] from fp32 h1 ----------------
__global__ __launch_bounds__(256) void k_scores1(const float* __restrict__ h1,
                                                 const float* __restrict__ att_src,
                                                 const float* __restrict__ att_dst,
                                                 float* __restrict__ as1,
                                                 float* __restrict__ ad1) {
  __shared__ float sa[8 * 33], sd[8 * 33];  // +1 pad per head row
  const int t = threadIdx.x;
  {
    int hh = t >> 5, cc = t & 31;
    sa[hh * 33 + cc] = att_src[t];
    sd[hh * 33 + cc] = att_dst[t];
  }
  __syncthreads();
  const int idx = blockIdx.x * 256 + t;
  const int head = idx & 7;
  const float4* p = (const float4*)(h1 + (size_t)(idx >> 3) * HC + head * 32);
  const float* sap = &sa[head * 33];
  const float* sdp = &sd[head * 33];
  float s_acc = 0.f, d_acc = 0.f;
#pragma unroll
  for (int q = 0; q < 8; ++q) {
    float4 v = p[q];
    const float f[4] = {v.x, v.y, v.z, v.w};
#pragma unroll
    for (int i = 0; i < 4; ++i) {
      int c = q * 4 + i;
      s_acc += f[i] * sap[c];
      d_acc += f[i] * sdp[c];
    }
  }
  as1[idx] = s_acc;
  ad1[idx] = d_acc;
}

// ---------------- CSR build ----------------
__global__ void k_count(const int* __restrict__ ei, int* __restrict__ counts) {
  int e = blockIdx.x * 256 + threadIdx.x;
  if (e < EE) atomicAdd(&counts[ei[EE + e]], 1);
}

__global__ void k_scan1(const int* __restrict__ counts, int* __restrict__ offs,
                        int* __restrict__ bsums) {
  __shared__ int s[256];
  const int t = threadIdx.x;
  const int i = blockIdx.x * 256 + t;
  int v = (i < NN) ? counts[i] : 0;
  s[t] = v;
  __syncthreads();
  for (int off = 1; off < 256; off <<= 1) {
    int tv = (t >= off) ? s[t - off] : 0;
    __syncthreads();
    s[t] += tv;
    __syncthreads();
  }
  if (i < NN) offs[i] = s[t] - v;
  if (t == 255) bsums[blockIdx.x] = s[255];
}

__global__ void k_scan2(int* __restrict__ bsums, int nb) {
  __shared__ int s[512];
  const int t = threadIdx.x;
  int v = (t < nb) ? bsums[t] : 0;
  s[t] = v;
  __syncthreads();
  for (int off = 1; off < 512; off <<= 1) {
    int tv = (t >= off) ? s[t - off] : 0;
    __syncthreads();
    s[t] += tv;
    __syncthreads();
  }
  if (t < nb) bsums[t] = s[t] - v;  // exclusive block offsets
}

__global__ void k_scan3(int* __restrict__ offs, const int* __restrict__ bsums,
                        int* __restrict__ cursor) {
  const int i = blockIdx.x * 256 + threadIdx.x;
  if (i < NN) {
    int v = offs[i] + bsums[i >> 8];
    offs[i] = v;
    cursor[i] = v;
  }
  if (i == 0) offs[NN] = EE;
}

__global__ void k_scatter(const int* __restrict__ ei, int* __restrict__ cursor,
                          int* __restrict__ esrc) {
  int e = blockIdx.x * 256 + threadIdx.x;
  if (e < EE) {
    int d = ei[EE + e];
    int p = atomicAdd(&cursor[d], 1);
    esrc[p] = ei[e];
  }
}

// ---------------- fused agg1 + bias + ELU + GEMM2 row ----------------
// one block (256 thr) per node; t = head*32 + c for the aggregation phase.
// After aggregation, out1 row (256 fp32) lives in LDS; compute h2 row (32)
// directly: h2[n,c] = sum_k out1[k] * W2[k,c].  W2 is 32KB -> L1-resident.
__global__ __launch_bounds__(256) void k_agg1(const float* __restrict__ h1,
                                              const float* __restrict__ as1,
                                              const float* __restrict__ ad1,
                                              const int* __restrict__ offs,
                                              const int* __restrict__ esrc,
                                              const float* __restrict__ b1,
                                              const float* __restrict__ W2,
                                              float* __restrict__ h2) {
  __shared__ float wl[32][8];
  __shared__ int sl[32];
  __shared__ float sv[256];
  __shared__ float sp[8][33];
  const int n = blockIdx.x;
  const int t = threadIdx.x;
  const int head = t >> 5;
  const int start = offs[n], end = offs[n + 1];
  const float ad = ad1[n * 8 + head];
  // self loop
  float w = __expf(lrelu(as1[n * 8 + head] + ad));
  float z = w;
  float acc = w * h1[(size_t)n * HC + t];
  for (int base = start; base < end; base += 32) {
    const int cnt = min(32, end - base);
    __syncthreads();
    const int j = t >> 3, hh = t & 7;
    if (j < cnt) {
      int s = esrc[base + j];
      if (hh == 0) sl[j] = s;
      wl[j][hh] = __expf(lrelu(as1[s * 8 + hh] + ad1[n * 8 + hh]));
    }
    __syncthreads();
#pragma unroll 4
    for (int j2 = 0; j2 < cnt; ++j2) {
      float w2 = wl[j2][head];
      z += w2;
      acc += w2 * h1[(size_t)sl[j2] * HC + t];
    }
  }
  float v = acc / (z + 1e-16f) + b1[t];
  v = v > 0.f ? v : (__expf(v) - 1.0f);   // ELU
  sv[t] = v;
  __syncthreads();
  // GEMM2 row: r = k-slice, c = output channel
  const int r = t >> 5, c = t & 31;
  const float* w2p = W2 + r * 32 * 32 + c;
  const float* svp = sv + r * 32;
  float p = 0.f;
#pragma unroll 8
  for (int kk = 0; kk < 32; ++kk) p += svp[kk] * w2p[kk * 32];
  sp[r][c] = p;
  __syncthreads();
  if (t < 32) {
    float hv = 0.f;
#pragma unroll
    for (int rr = 0; rr < 8; ++rr) hv += sp[rr][t];
    h2[(size_t)n * 32 + t] = hv;
  }
}

// ---------------- scores2 (fp32 h2) ----------------
__global__ __launch_bounds__(256) void k_scores2(const float* __restrict__ h2,
                                                 const float* __restrict__ att_src,
                                                 const float* __restrict__ att_dst,
                                                 float* __restrict__ as2,
                                                 float* __restrict__ ad2) {
  __shared__ float sa[32], sd[32];
  const int t = threadIdx.x;
  if (t < 32) { sa[t] = att_src[t]; sd[t] = att_dst[t]; }
  __syncthreads();
  const int n = blockIdx.x * 256 + t;
  if (n < NN) {
    const float4* p = (const float4*)(h2 + (size_t)n * 32);
    float s_acc = 0.f, d_acc = 0.f;
#pragma unroll
    for (int q = 0; q < 8; ++q) {
      float4 v = p[q];
      const float f[4] = {v.x, v.y, v.z, v.w};
#pragma unroll
      for (int i = 0; i < 4; ++i) {
        int c = q * 4 + i;
        s_acc += f[i] * sa[c];
        d_acc += f[i] * sd[c];
      }
    }
    as2[n] = s_acc;
    ad2[n] = d_acc;
  }
}

// ---------------- agg2 + fused mean-pool accumulation ----------------
// 8 nodes per block (32 threads each)
__global__ __launch_bounds__(256) void k_agg2(const float* __restrict__ h2,
                                              const float* __restrict__ as2,
                                              const float* __restrict__ ad2,
                                              const int* __restrict__ offs,
                                              const int* __restrict__ esrc,
                                              const float* __restrict__ b2,
                                              const int* __restrict__ batch,
                                              float* __restrict__ sums,
                                              float* __restrict__ gcnt) {
  __shared__ int lh[GG];
  const int t = threadIdx.x;
  if (t < GG) lh[t] = 0;
  const int g = t >> 5, c = t & 31;
  const int n = blockIdx.x * 8 + g;
  const int start = offs[n], end = offs[n + 1];
  const float adn = ad2[n];
  float w = __expf(lrelu(as2[n] + adn));
  float z = w;
  float acc = w * h2[(size_t)n * 32 + c];
#pragma unroll 4
  for (int e = start; e < end; ++e) {
    int s = esrc[e];
    float w2 = __expf(lrelu(as2[s] + adn));
    z += w2;
    acc += w2 * h2[(size_t)s * 32 + c];
  }
  float v = acc / (z + 1e-16f) + b2[c];
  int gid = batch[n];
  atomicAdd(&sums[gid * 32 + c], v);
  __syncthreads();
  if (c == 0) atomicAdd(&lh[gid], 1);
  __syncthreads();
  if (t < GG && lh[t] > 0) atomicAdd(&gcnt[t], (float)lh[t]);
}

// ---------------- final: (sums/cnt) @ Wlin + blin ----------------
__global__ void k_final(const float* __restrict__ sums, const float* __restrict__ gcnt,
                        const float* __restrict__ Wlin, const float* __restrict__ blin,
                        float* __restrict__ out) {
  const int t = threadIdx.x;
  if (t < GG * NC) {
    int g = t / NC, k = t % NC;
    float cnt = gcnt[g];
    cnt = cnt > 1.f ? cnt : 1.f;
    float a = 0.f;
#pragma unroll
    for (int c = 0; c < 32; ++c) a += (sums[g * 32 + c] / cnt) * Wlin[c * NC + k];
    out[t] = a + blin[k];
  }
}

extern "C" void kernel_launch(void* const* d_in, const int* in_sizes, int n_in,
                              void* d_out, int out_size, void* d_ws, size_t ws_size,
                              hipStream_t stream) {
  const float* x        = (const float*)d_in[0];
  const int*   ei       = (const int*)d_in[1];
  const int*   batch    = (const int*)d_in[2];
  const float* W1       = (const float*)d_in[3];
  const float* att_src1 = (const float*)d_in[4];
  const float* att_dst1 = (const float*)d_in[5];
  const float* b1       = (const float*)d_in[6];
  const float* W2       = (const float*)d_in[7];
  const float* att_src2 = (const float*)d_in[8];
  const float* att_dst2 = (const float*)d_in[9];
  const float* b2       = (const float*)d_in[10];
  const float* Wlin     = (const float*)d_in[11];
  const float* blin     = (const float*)d_in[12];
  float* out = (float*)d_out;
  char* ws = (char*)d_ws;

  // workspace layout (bytes), all fp32 intermediates  (~130 MB total)
  float* h1    = (float*)(ws + 0);              // 102,400,000
  float* as1   = (float*)(ws + 102400000);      // 3,200,000
  float* ad1   = (float*)(ws + 105600000);      // 3,200,000
  int* counts  = (int*)(ws + 108800000);        // 400,000
  int* offs    = (int*)(ws + 109200000);        // 400,004 (+pad)
  int* cursor  = (int*)(ws + 109600256);        // 400,000
  int* esrc    = (int*)(ws + 110000256);        // 6,400,000
  int* bsums   = (int*)(ws + 116400256);        // 1,564 (+pad)
  float* sums  = (float*)(ws + 116402048);      // 8,192
  float* gcnt  = (float*)(ws + 116410240);      // 256
  float* h2    = (float*)(ws + 116410496);      // 12,800,000
  float* as2   = (float*)(ws + 129210496);      // 400,000
  float* ad2   = (float*)(ws + 129610496);      // 400,000

  const int nb_scan = (NN + 255) / 256;  // 391

  k_zero<<<nb_scan, 256, 0, stream>>>((unsigned int*)counts, NN);
  k_zero<<<9, 256, 0, stream>>>((unsigned int*)sums, 2048 + 64);

  k_gemm1<<<(NN + 63) / 64, 256, 0, stream>>>(x, W1, h1);
  k_scores1<<<(NN * 8) / 256, 256, 0, stream>>>(h1, att_src1, att_dst1, as1, ad1);

  k_count<<<(EE + 255) / 256, 256, 0, stream>>>(ei, counts);
  k_scan1<<<nb_scan, 256, 0, stream>>>(counts, offs, bsums);
  k_scan2<<<1, 512, 0, stream>>>(bsums, nb_scan);
  k_scan3<<<nb_scan, 256, 0, stream>>>(offs, bsums, cursor);
  k_scatter<<<(EE + 255) / 256, 256, 0, stream>>>(ei, cursor, esrc);

  k_agg1<<<NN, 256, 0, stream>>>(h1, as1, ad1, offs, esrc, b1, W2, h2);

  k_scores2<<<nb_scan, 256, 0, stream>>>(h2, att_src2, att_dst2, as2, ad2);
  k_agg2<<<NN / 8, 256, 0, stream>>>(h2, as2, ad2, offs, esrc, b2, batch, sums, gcnt);

  k_final<<<1, 640, 0, stream>>>(sums, gcnt, Wlin, blin, out);
}

// Round 3
// 839.170 us; speedup vs baseline: 1.2787x; 1.2787x over previous
//
#include <hip/hip_runtime.h>
#include <cstdint>

#define NN 100000
#define EE 1600000
#define GG 64
#define FIN 128
#define HC 256      // H*C for layer 1
#define NC 10

static __device__ __forceinline__ float lrelu(float x) { return x > 0.f ? x : 0.2f * x; }

// ---------------- utility ----------------
__global__ void k_zero(unsigned int* __restrict__ p, int n) {
  int i = blockIdx.x * 256 + threadIdx.x;
  if (i < n) p[i] = 0u;
}

// ---------------- GEMM1: h1 = x @ W1  (fp32 in, fp32 out) ----------------
// tile 64 rows x 256 cols, K=128, k-chunk 8. thread: 4 rows x 16 cols (4 col groups of 4)
__global__ __launch_bounds__(256) void k_gemm1(const float* __restrict__ x,
                                               const float* __restrict__ W1,
                                               float* __restrict__ h1) {
  __shared__ float As[8][64];
  __shared__ float Bs[8][256];
  const int t = threadIdx.x;
  const int m0 = blockIdx.x * 64;
  const int tx = t & 15;
  const int ty = t >> 4;
  float4 acc[4][4];
#pragma unroll
  for (int j = 0; j < 4; ++j)
#pragma unroll
    for (int r = 0; r < 4; ++r) acc[j][r] = make_float4(0.f, 0.f, 0.f, 0.f);

  for (int k0 = 0; k0 < FIN; k0 += 8) {
    __syncthreads();
    if (t < 128) {
      int m = t >> 1;
      int kk = (t & 1) * 4;
      int row = m0 + m; if (row >= NN) row = NN - 1;
      const float4 xv = *(const float4*)(x + row * FIN + k0 + kk);
      As[kk + 0][m] = xv.x; As[kk + 1][m] = xv.y;
      As[kk + 2][m] = xv.z; As[kk + 3][m] = xv.w;
    }
#pragma unroll
    for (int i = 0; i < 8; ++i) Bs[i][t] = W1[(k0 + i) * HC + t];
    __syncthreads();
#pragma unroll
    for (int k = 0; k < 8; ++k) {
      const float4 a4 = *(const float4*)&As[k][ty * 4];
      const float ar[4] = {a4.x, a4.y, a4.z, a4.w};
#pragma unroll
      for (int j = 0; j < 4; ++j) {
        const float4 b4 = *(const float4*)&Bs[k][tx * 4 + 64 * j];
#pragma unroll
        for (int r = 0; r < 4; ++r) {
          acc[j][r].x += ar[r] * b4.x; acc[j][r].y += ar[r] * b4.y;
          acc[j][r].z += ar[r] * b4.z; acc[j][r].w += ar[r] * b4.w;
        }
      }
    }
  }
#pragma unroll
  for (int r = 0; r < 4; ++r) {
    int row = m0 + ty * 4 + r;
    if (row < NN) {
#pragma unroll
      for (int j = 0; j < 4; ++j) {
        *(float4*)(h1 + (size_t)row * HC + tx * 4 + 64 * j) = acc[j][r];
      }
    }
  }
}

// ---------------- scores1: a_s[n,h], a_d[n,h] from fp32 h1 ----------------
__global__ __launch_bounds__(256) void k_scores1(const float* __restrict__ h1,
                                                 const float* __restrict__ att_src,
                                                 const float* __restrict__ att_dst,
                                                 float* __restrict__ as1,
                                                 float* __restrict__ ad1) {
  __shared__ float sa[8 * 33], sd[8 * 33];  // +1 pad per head row
  const int t = threadIdx.x;
  {
    int hh = t >> 5, cc = t & 31;
    sa[hh * 33 + cc] = att_src[t];
    sd[hh * 33 + cc] = att_dst[t];
  }
  __syncthreads();
  const int idx = blockIdx.x * 256 + t;
  const int head = idx & 7;
  const float4* p = (const float4*)(h1 + (size_t)(idx >> 3) * HC + head * 32);
  const float* sap = &sa[head * 33];
  const float* sdp = &sd[head * 33];
  float s_acc = 0.f, d_acc = 0.f;
#pragma unroll
  for (int q = 0; q < 8; ++q) {
    float4 v = p[q];
    const float f[4] = {v.x, v.y, v.z, v.w};
#pragma unroll
    for (int i = 0; i < 4; ++i) {
      int c = q * 4 + i;
      s_acc += f[i] * sap[c];
      d_acc += f[i] * sdp[c];
    }
  }
  as1[idx] = s_acc;
  ad1[idx] = d_acc;
}

// ---------------- CSR build ----------------
__global__ void k_count(const int* __restrict__ ei, int* __restrict__ counts) {
  int e = blockIdx.x * 256 + threadIdx.x;
  if (e < EE) atomicAdd(&counts[ei[EE + e]], 1);
}

__global__ void k_scan1(const int* __restrict__ counts, int* __restrict__ offs,
                        int* __restrict__ bsums) {
  __shared__ int s[256];
  const int t = threadIdx.x;
  const int i = blockIdx.x * 256 + t;
  int v = (i < NN) ? counts[i] : 0;
  s[t] = v;
  __syncthreads();
  for (int off = 1; off < 256; off <<= 1) {
    int tv = (t >= off) ? s[t - off] : 0;
    __syncthreads();
    s[t] += tv;
    __syncthreads();
  }
  if (i < NN) offs[i] = s[t] - v;
  if (t == 255) bsums[blockIdx.x] = s[255];
}

__global__ void k_scan2(int* __restrict__ bsums, int nb) {
  __shared__ int s[512];
  const int t = threadIdx.x;
  int v = (t < nb) ? bsums[t] : 0;
  s[t] = v;
  __syncthreads();
  for (int off = 1; off < 512; off <<= 1) {
    int tv = (t >= off) ? s[t - off] : 0;
    __syncthreads();
    s[t] += tv;
    __syncthreads();
  }
  if (t < nb) bsums[t] = s[t] - v;  // exclusive block offsets
}

__global__ void k_scan3(int* __restrict__ offs, const int* __restrict__ bsums,
                        int* __restrict__ cursor) {
  const int i = blockIdx.x * 256 + threadIdx.x;
  if (i < NN) {
    int v = offs[i] + bsums[i >> 8];
    offs[i] = v;
    cursor[i] = v;
  }
  if (i == 0) offs[NN] = EE;
}

__global__ void k_scatter(const int* __restrict__ ei, int* __restrict__ cursor,
                          int* __restrict__ esrc) {
  int e = blockIdx.x * 256 + threadIdx.x;
  if (e < EE) {
    int d = ei[EE + e];
    int p = atomicAdd(&cursor[d], 1);
    esrc[p] = ei[e];
  }
}

// ---------------- fused agg1 + bias + ELU + GEMM2 row + scores2 ----------------
// one block (256 thr) per node; t = head*32 + c for the aggregation phase.
// After aggregation, out1 row (256 fp32) lives in LDS; compute h2 row (32)
// directly (W2 is 32KB -> L1-resident), then as2/ad2 via wave reduce.
__global__ __launch_bounds__(256) void k_agg1(const float* __restrict__ h1,
                                              const float* __restrict__ as1,
                                              const float* __restrict__ ad1,
                                              const int* __restrict__ offs,
                                              const int* __restrict__ esrc,
                                              const float* __restrict__ b1,
                                              const float* __restrict__ W2,
                                              const float* __restrict__ att_src2,
                                              const float* __restrict__ att_dst2,
                                              float* __restrict__ h2,
                                              float* __restrict__ as2,
                                              float* __restrict__ ad2) {
  __shared__ float wl[32][8];
  __shared__ int sl[32];
  __shared__ float sv[256];
  __shared__ float sp[8][33];
  const int n = blockIdx.x;
  const int t = threadIdx.x;
  const int head = t >> 5;
  const int start = offs[n], end = offs[n + 1];
  const float ad = ad1[n * 8 + head];
  // self loop
  float w = __expf(lrelu(as1[n * 8 + head] + ad));
  float z = w;
  float acc = w * h1[(size_t)n * HC + t];
  for (int base = start; base < end; base += 32) {
    const int cnt = min(32, end - base);
    __syncthreads();
    const int j = t >> 3, hh = t & 7;
    if (j < cnt) {
      int s = esrc[base + j];
      if (hh == 0) sl[j] = s;
      wl[j][hh] = __expf(lrelu(as1[s * 8 + hh] + ad1[n * 8 + hh]));
    }
    __syncthreads();
#pragma unroll 4
    for (int j2 = 0; j2 < cnt; ++j2) {
      float w2 = wl[j2][head];
      z += w2;
      acc += w2 * h1[(size_t)sl[j2] * HC + t];
    }
  }
  float v = acc / (z + 1e-16f) + b1[t];
  v = v > 0.f ? v : (__expf(v) - 1.0f);   // ELU
  sv[t] = v;
  __syncthreads();
  // GEMM2 row: r = k-slice, c = output channel
  const int r = t >> 5, c = t & 31;
  const float* w2p = W2 + r * 32 * 32 + c;
  const float* svp = sv + r * 32;
  float p = 0.f;
#pragma unroll 8
  for (int kk = 0; kk < 32; ++kk) p += svp[kk] * w2p[kk * 32];
  sp[r][c] = p;
  __syncthreads();
  if (t < 32) {
    float hv = 0.f;
#pragma unroll
    for (int rr = 0; rr < 8; ++rr) hv += sp[rr][t];
    h2[(size_t)n * 32 + t] = hv;
    // fused scores2: wave-reduce over the 32 channels (lanes 0..31 of wave 0)
    float ps = hv * att_src2[t];
    float pd = hv * att_dst2[t];
#pragma unroll
    for (int m = 16; m >= 1; m >>= 1) {
      ps += __shfl_xor(ps, m, 64);
      pd += __shfl_xor(pd, m, 64);
    }
    if (t == 0) { as2[n] = ps; ad2[n] = pd; }
  }
}

// ---------------- agg2: softmax-weighted sum -> dense h3 (no atomics) ----------------
// 8 nodes per block, 32 lanes per node. Weights computed edge-parallel across
// the 32 lanes, broadcast via __shfl (register-only; no LDS, no barriers).
__global__ __launch_bounds__(256) void k_agg2(const float* __restrict__ h2,
                                              const float* __restrict__ as2,
                                              const float* __restrict__ ad2,
                                              const int* __restrict__ offs,
                                              const int* __restrict__ esrc,
                                              const float* __restrict__ b2,
                                              float* __restrict__ h3) {
  const int t = threadIdx.x;
  const int g = t >> 5, c = t & 31;
  const int n = blockIdx.x * 8 + g;
  const int sbase = t & 32;  // group base lane within the 64-lane wave
  const int start = offs[n], end = offs[n + 1];
  const float adn = ad2[n];
  float w0 = __expf(lrelu(as2[n] + adn));
  float z = w0;
  float acc = w0 * h2[(size_t)n * 32 + c];
  for (int base = start; base < end; base += 32) {
    const int cnt = min(32, end - base);
    int s_reg = 0; float w_reg = 0.f;
    if (c < cnt) {
      s_reg = esrc[base + c];
      w_reg = __expf(lrelu(as2[s_reg] + adn));
    }
#pragma unroll 4
    for (int j = 0; j < cnt; ++j) {
      int sj = __shfl(s_reg, sbase + j, 64);
      float wj = __shfl(w_reg, sbase + j, 64);
      z += wj;
      acc += wj * h2[(size_t)sj * 32 + c];
    }
  }
  h3[(size_t)n * 32 + c] = acc / (z + 1e-16f) + b2[c];
}

// ---------------- pool: atomic-free segment mean via binary search ----------------
__global__ __launch_bounds__(256) void k_pool(const float* __restrict__ h3,
                                              const int* __restrict__ batch,
                                              float* __restrict__ sums,
                                              float* __restrict__ cnts) {
  __shared__ int bounds[2];
  __shared__ float red[8][33];
  const int g = blockIdx.x;
  const int t = threadIdx.x;
  if (t < 2) {
    int target = g + t;
    int lo = 0, hi = NN;
    while (lo < hi) { int mid = (lo + hi) >> 1; if (batch[mid] < target) lo = mid + 1; else hi = mid; }
    bounds[t] = lo;
  }
  __syncthreads();
  const int lo = bounds[0], hi = bounds[1];
  const int rr = t >> 5, c = t & 31;
  float a = 0.f;
  for (int r = lo + rr; r < hi; r += 8) a += h3[(size_t)r * 32 + c];
  red[rr][c] = a;
  __syncthreads();
  if (rr == 0) {
    float s = 0.f;
#pragma unroll
    for (int i = 0; i < 8; ++i) s += red[i][c];
    sums[g * 32 + c] = s;
    if (c == 0) cnts[g] = (float)(hi - lo);
  }
}

// ---------------- final: (sums/cnt) @ Wlin + blin ----------------
__global__ void k_final(const float* __restrict__ sums, const float* __restrict__ cnts,
                        const float* __restrict__ Wlin, const float* __restrict__ blin,
                        float* __restrict__ out) {
  const int t = threadIdx.x;
  if (t < GG * NC) {
    int g = t / NC, k = t % NC;
    float cnt = cnts[g];
    cnt = cnt > 1.f ? cnt : 1.f;
    float a = 0.f;
#pragma unroll
    for (int c = 0; c < 32; ++c) a += (sums[g * 32 + c] / cnt) * Wlin[c * NC + k];
    out[t] = a + blin[k];
  }
}

extern "C" void kernel_launch(void* const* d_in, const int* in_sizes, int n_in,
                              void* d_out, int out_size, void* d_ws, size_t ws_size,
                              hipStream_t stream) {
  const float* x        = (const float*)d_in[0];
  const int*   ei       = (const int*)d_in[1];
  const int*   batch    = (const int*)d_in[2];
  const float* W1       = (const float*)d_in[3];
  const float* att_src1 = (const float*)d_in[4];
  const float* att_dst1 = (const float*)d_in[5];
  const float* b1       = (const float*)d_in[6];
  const float* W2       = (const float*)d_in[7];
  const float* att_src2 = (const float*)d_in[8];
  const float* att_dst2 = (const float*)d_in[9];
  const float* b2       = (const float*)d_in[10];
  const float* Wlin     = (const float*)d_in[11];
  const float* blin     = (const float*)d_in[12];
  float* out = (float*)d_out;
  char* ws = (char*)d_ws;

  // workspace layout (bytes), all fp32 intermediates  (~130 MB total)
  float* h1    = (float*)(ws + 0);              // 102,400,000
  float* as1   = (float*)(ws + 102400000);      // 3,200,000
  float* ad1   = (float*)(ws + 105600000);      // 3,200,000
  int* counts  = (int*)(ws + 108800000);        // 400,000
  int* offs    = (int*)(ws + 109200000);        // 400,004 (+pad)
  int* cursor  = (int*)(ws + 109600256);        // 400,000
  int* esrc    = (int*)(ws + 110000256);        // 6,400,000
  int* bsums   = (int*)(ws + 116400256);        // 1,564 (+pad)
  float* sums  = (float*)(ws + 116402048);      // 8,192
  float* cnts  = (float*)(ws + 116410240);      // 256
  float* h2    = (float*)(ws + 116410496);      // 12,800,000
  float* as2   = (float*)(ws + 129210496);      // 400,000
  float* ad2   = (float*)(ws + 129610496);      // 400,000
  // h1 is dead after k_agg1 -> overlay h3 on its region
  float* h3    = (float*)(ws + 0);              // 12,800,000

  const int nb_scan = (NN + 255) / 256;  // 391

  k_zero<<<nb_scan, 256, 0, stream>>>((unsigned int*)counts, NN);

  k_gemm1<<<(NN + 63) / 64, 256, 0, stream>>>(x, W1, h1);
  k_scores1<<<(NN * 8) / 256, 256, 0, stream>>>(h1, att_src1, att_dst1, as1, ad1);

  k_count<<<(EE + 255) / 256, 256, 0, stream>>>(ei, counts);
  k_scan1<<<nb_scan, 256, 0, stream>>>(counts, offs, bsums);
  k_scan2<<<1, 512, 0, stream>>>(bsums, nb_scan);
  k_scan3<<<nb_scan, 256, 0, stream>>>(offs, bsums, cursor);
  k_scatter<<<(EE + 255) / 256, 256, 0, stream>>>(ei, cursor, esrc);

  k_agg1<<<NN, 256, 0, stream>>>(h1, as1, ad1, offs, esrc, b1, W2,
                                 att_src2, att_dst2, h2, as2, ad2);

  k_agg2<<<NN / 8, 256, 0, stream>>>(h2, as2, ad2, offs, esrc, b2, h3);
  k_pool<<<GG, 256, 0, stream>>>(h3, batch, sums, cnts);

  k_final<<<1, 640, 0, stream>>>(sums, cnts, Wlin, blin, out);
}

// Round 4
// 789.012 us; speedup vs baseline: 1.3600x; 1.0636x over previous
//
#include <hip/hip_runtime.h>
#include <cstdint>

#define NN 100000
#define EE 1600000
#define GG 64
#define FIN 128
#define HC 256      // H*C for layer 1
#define NC 10

static __device__ __forceinline__ float lrelu(float x) { return x > 0.f ? x : 0.2f * x; }
static __device__ __forceinline__ unsigned short f2bf(float f) {
  unsigned int u = __float_as_uint(f);
  unsigned int r = (u + 0x7FFFu + ((u >> 16) & 1u)) >> 16;
  return (unsigned short)r;
}
static __device__ __forceinline__ void unpack2(unsigned int u, float& f0, float& f1) {
  f0 = __uint_as_float(u << 16);          // even channel (lo ushort)
  f1 = __uint_as_float(u & 0xFFFF0000u);  // odd channel (hi ushort)
}

// ---------------- utility ----------------
__global__ void k_zero(unsigned int* __restrict__ p, int n) {
  int i = blockIdx.x * 256 + threadIdx.x;
  if (i < n) p[i] = 0u;
}

// ---------------- GEMM1 + fused scores1 ----------------
// h1b(bf16) = x @ W1 ; as1/ad1 = per-(row,head) dots with att vectors,
// computed from fp32 accumulators via 8-lane shuffle reduction.
// tile 64 rows x 256 cols, K=128, k-chunk 8. thread: 4 rows x 16 cols.
__global__ __launch_bounds__(256) void k_gemm1(const float* __restrict__ x,
                                               const float* __restrict__ W1,
                                               const float* __restrict__ att_src1,
                                               const float* __restrict__ att_dst1,
                                               unsigned short* __restrict__ h1b,
                                               float* __restrict__ as1,
                                               float* __restrict__ ad1) {
  __shared__ float As[8][64];
  __shared__ float Bs[8][256];
  const int t = threadIdx.x;
  const int m0 = blockIdx.x * 64;
  const int tx = t & 15;
  const int ty = t >> 4;
  float4 acc[4][4];
#pragma unroll
  for (int j = 0; j < 4; ++j)
#pragma unroll
    for (int r = 0; r < 4; ++r) acc[j][r] = make_float4(0.f, 0.f, 0.f, 0.f);

  for (int k0 = 0; k0 < FIN; k0 += 8) {
    __syncthreads();
    if (t < 128) {
      int m = t >> 1;
      int kk = (t & 1) * 4;
      int row = m0 + m; if (row >= NN) row = NN - 1;
      const float4 xv = *(const float4*)(x + row * FIN + k0 + kk);
      As[kk + 0][m] = xv.x; As[kk + 1][m] = xv.y;
      As[kk + 2][m] = xv.z; As[kk + 3][m] = xv.w;
    }
#pragma unroll
    for (int i = 0; i < 8; ++i) Bs[i][t] = W1[(k0 + i) * HC + t];
    __syncthreads();
#pragma unroll
    for (int k = 0; k < 8; ++k) {
      const float4 a4 = *(const float4*)&As[k][ty * 4];
      const float ar[4] = {a4.x, a4.y, a4.z, a4.w};
#pragma unroll
      for (int j = 0; j < 4; ++j) {
        const float4 b4 = *(const float4*)&Bs[k][tx * 4 + 64 * j];
#pragma unroll
        for (int r = 0; r < 4; ++r) {
          acc[j][r].x += ar[r] * b4.x; acc[j][r].y += ar[r] * b4.y;
          acc[j][r].z += ar[r] * b4.z; acc[j][r].w += ar[r] * b4.w;
        }
      }
    }
  }
  // epilogue: bf16 store + fused attention scores
  const int txl = tx & 7;   // position within the 8-lane head group
  const int hsel = tx >> 3; // 0 or 1: which of the two heads in col group j
  float4 avs[4], avd[4];
#pragma unroll
  for (int j = 0; j < 4; ++j) {
    int h = 2 * j + hsel;
    avs[j] = *(const float4*)(att_src1 + h * 32 + txl * 4);
    avd[j] = *(const float4*)(att_dst1 + h * 32 + txl * 4);
  }
#pragma unroll
  for (int r = 0; r < 4; ++r) {
    int row = m0 + ty * 4 + r;
    bool ok = row < NN;
#pragma unroll
    for (int j = 0; j < 4; ++j) {
      float4 a = acc[j][r];
      if (ok) {
        ushort4 u;
        u.x = f2bf(a.x); u.y = f2bf(a.y); u.z = f2bf(a.z); u.w = f2bf(a.w);
        *(ushort4*)(h1b + (size_t)row * HC + tx * 4 + 64 * j) = u;
      }
      float vs = a.x * avs[j].x + a.y * avs[j].y + a.z * avs[j].z + a.w * avs[j].w;
      float vd = a.x * avd[j].x + a.y * avd[j].y + a.z * avd[j].z + a.w * avd[j].w;
      vs += __shfl_xor(vs, 1, 64); vs += __shfl_xor(vs, 2, 64); vs += __shfl_xor(vs, 4, 64);
      vd += __shfl_xor(vd, 1, 64); vd += __shfl_xor(vd, 2, 64); vd += __shfl_xor(vd, 4, 64);
      if (ok && txl == 0) {
        as1[row * 8 + 2 * j + hsel] = vs;
        ad1[row * 8 + 2 * j + hsel] = vd;
      }
    }
  }
}

// ---------------- CSR build ----------------
__global__ void k_count(const int* __restrict__ ei, int* __restrict__ counts) {
  int e = blockIdx.x * 256 + threadIdx.x;
  if (e < EE) atomicAdd(&counts[ei[EE + e]], 1);
}

__global__ void k_scan1(const int* __restrict__ counts, int* __restrict__ offs,
                        int* __restrict__ bsums) {
  __shared__ int s[256];
  const int t = threadIdx.x;
  const int i = blockIdx.x * 256 + t;
  int v = (i < NN) ? counts[i] : 0;
  s[t] = v;
  __syncthreads();
  for (int off = 1; off < 256; off <<= 1) {
    int tv = (t >= off) ? s[t - off] : 0;
    __syncthreads();
    s[t] += tv;
    __syncthreads();
  }
  if (i < NN) offs[i] = s[t] - v;
  if (t == 255) bsums[blockIdx.x] = s[255];
}

__global__ void k_scan2(int* __restrict__ bsums, int nb) {
  __shared__ int s[512];
  const int t = threadIdx.x;
  int v = (t < nb) ? bsums[t] : 0;
  s[t] = v;
  __syncthreads();
  for (int off = 1; off < 512; off <<= 1) {
    int tv = (t >= off) ? s[t - off] : 0;
    __syncthreads();
    s[t] += tv;
    __syncthreads();
  }
  if (t < nb) bsums[t] = s[t] - v;
}

__global__ void k_scan3(int* __restrict__ offs, const int* __restrict__ bsums,
                        int* __restrict__ cursor) {
  const int i = blockIdx.x * 256 + threadIdx.x;
  if (i < NN) {
    int v = offs[i] + bsums[i >> 8];
    offs[i] = v;
    cursor[i] = v;
  }
  if (i == 0) offs[NN] = EE;
}

__global__ void k_scatter(const int* __restrict__ ei, int* __restrict__ cursor,
                          int* __restrict__ esrc) {
  int e = blockIdx.x * 256 + threadIdx.x;
  if (e < EE) {
    int d = ei[EE + e];
    int p = atomicAdd(&cursor[d], 1);
    esrc[p] = ei[e];
  }
}

// ---------------- fused agg1 + bias + ELU + GEMM2 row + scores2 ----------------
// 128 threads per node; thread t owns channel pair (2t, 2t+1); head = t>>4.
// Gather payload is bf16x2 (one dword per thread per edge) with a scalar
// (readfirstlane) row base -> global_load with SGPR base + small voffset.
__global__ __launch_bounds__(128) void k_agg1(const unsigned short* __restrict__ h1b,
                                              const float* __restrict__ as1,
                                              const float* __restrict__ ad1,
                                              const int* __restrict__ offs,
                                              const int* __restrict__ esrc,
                                              const float* __restrict__ b1,
                                              const float* __restrict__ W2,
                                              const float* __restrict__ att_src2,
                                              const float* __restrict__ att_dst2,
                                              float* __restrict__ h2,
                                              float* __restrict__ as2,
                                              float* __restrict__ ad2) {
  __shared__ float wl[32][8];
  __shared__ int sl[32];
  __shared__ float adl[8];
  __shared__ float sv[256];
  __shared__ float sp[4][33];
  const int n = blockIdx.x;
  const int t = threadIdx.x;      // 0..127
  const int head = t >> 4;        // 0..7
  const int start = offs[n], end = offs[n + 1];
  if (t < 8) adl[t] = ad1[n * 8 + t];
  __syncthreads();
  const float ad = adl[head];
  const unsigned int* h1u = (const unsigned int*)h1b;

  float w0 = __expf(lrelu(as1[n * 8 + head] + ad));
  float z = w0;
  float f0, f1;
  unpack2(h1u[(size_t)n * 128 + t], f0, f1);
  float acc0 = w0 * f0, acc1 = w0 * f1;

  for (int base = start; base < end; base += 32) {
    const int cnt = min(32, end - base);
    __syncthreads();
    const int j = t >> 2, hh = (t & 3) * 2;
    if (j < cnt) {
      int s = esrc[base + j];
      if (hh == 0) sl[j] = s;
      float2 av = *(const float2*)(as1 + s * 8 + hh);
      wl[j][hh]     = __expf(lrelu(av.x + adl[hh]));
      wl[j][hh + 1] = __expf(lrelu(av.y + adl[hh + 1]));
    }
    __syncthreads();
#pragma unroll 4
    for (int j2 = 0; j2 < cnt; ++j2) {
      int sj = __builtin_amdgcn_readfirstlane(sl[j2]);
      float w2 = wl[j2][head];
      float g0, g1;
      unpack2(h1u[(size_t)sj * 128 + t], g0, g1);
      z += w2;
      acc0 += w2 * g0;
      acc1 += w2 * g1;
    }
  }
  const float zi = 1.0f / (z + 1e-16f);
  const float2 bb = *(const float2*)(b1 + 2 * t);
  float v0 = acc0 * zi + bb.x;
  float v1 = acc1 * zi + bb.y;
  v0 = v0 > 0.f ? v0 : (__expf(v0) - 1.0f);
  v1 = v1 > 0.f ? v1 : (__expf(v1) - 1.0f);
  *(float2*)(sv + 2 * t) = make_float2(v0, v1);
  __syncthreads();
  // GEMM2 row: 4 k-slices of 64, c = output channel
  const int c = t & 31, rr = t >> 5;
  const float* svp = sv + rr * 64;
  const float* w2p = W2 + rr * 64 * 32 + c;
  float p = 0.f;
#pragma unroll 16
  for (int kk = 0; kk < 64; ++kk) p += svp[kk] * w2p[kk * 32];
  sp[rr][c] = p;
  __syncthreads();
  if (t < 32) {
    float hv = sp[0][t] + sp[1][t] + sp[2][t] + sp[3][t];
    h2[(size_t)n * 32 + t] = hv;
    float ps = hv * att_src2[t];
    float pd = hv * att_dst2[t];
#pragma unroll
    for (int m = 16; m >= 1; m >>= 1) {
      ps += __shfl_xor(ps, m, 64);
      pd += __shfl_xor(pd, m, 64);
    }
    if (t == 0) { as2[n] = ps; ad2[n] = pd; }
  }
}

// ---------------- agg2: softmax-weighted sum -> dense h3 (no atomics) ----------------
__global__ __launch_bounds__(256) void k_agg2(const float* __restrict__ h2,
                                              const float* __restrict__ as2,
                                              const float* __restrict__ ad2,
                                              const int* __restrict__ offs,
                                              const int* __restrict__ esrc,
                                              const float* __restrict__ b2,
                                              float* __restrict__ h3) {
  const int t = threadIdx.x;
  const int g = t >> 5, c = t & 31;
  const int n = blockIdx.x * 8 + g;
  const int sbase = t & 32;
  const int start = offs[n], end = offs[n + 1];
  const float adn = ad2[n];
  float w0 = __expf(lrelu(as2[n] + adn));
  float z = w0;
  float acc = w0 * h2[(size_t)n * 32 + c];
  for (int base = start; base < end; base += 32) {
    const int cnt = min(32, end - base);
    int s_reg = 0; float w_reg = 0.f;
    if (c < cnt) {
      s_reg = esrc[base + c];
      w_reg = __expf(lrelu(as2[s_reg] + adn));
    }
#pragma unroll 4
    for (int j = 0; j < cnt; ++j) {
      int sj = __shfl(s_reg, sbase + j, 64);
      float wj = __shfl(w_reg, sbase + j, 64);
      z += wj;
      acc += wj * h2[(size_t)sj * 32 + c];
    }
  }
  h3[(size_t)n * 32 + c] = acc / (z + 1e-16f) + b2[c];
}

// ---------------- pool: atomic-free segment mean via binary search ----------------
__global__ __launch_bounds__(256) void k_pool(const float* __restrict__ h3,
                                              const int* __restrict__ batch,
                                              float* __restrict__ sums,
                                              float* __restrict__ cnts) {
  __shared__ int bounds[2];
  __shared__ float red[8][33];
  const int g = blockIdx.x;
  const int t = threadIdx.x;
  if (t < 2) {
    int target = g + t;
    int lo = 0, hi = NN;
    while (lo < hi) { int mid = (lo + hi) >> 1; if (batch[mid] < target) lo = mid + 1; else hi = mid; }
    bounds[t] = lo;
  }
  __syncthreads();
  const int lo = bounds[0], hi = bounds[1];
  const int rr = t >> 5, c = t & 31;
  float a = 0.f;
  for (int r = lo + rr; r < hi; r += 8) a += h3[(size_t)r * 32 + c];
  red[rr][c] = a;
  __syncthreads();
  if (rr == 0) {
    float s = 0.f;
#pragma unroll
    for (int i = 0; i < 8; ++i) s += red[i][c];
    sums[g * 32 + c] = s;
    if (c == 0) cnts[g] = (float)(hi - lo);
  }
}

// ---------------- final ----------------
__global__ void k_final(const float* __restrict__ sums, const float* __restrict__ cnts,
                        const float* __restrict__ Wlin, const float* __restrict__ blin,
                        float* __restrict__ out) {
  const int t = threadIdx.x;
  if (t < GG * NC) {
    int g = t / NC, k = t % NC;
    float cnt = cnts[g];
    cnt = cnt > 1.f ? cnt : 1.f;
    float a = 0.f;
#pragma unroll
    for (int c = 0; c < 32; ++c) a += (sums[g * 32 + c] / cnt) * Wlin[c * NC + k];
    out[t] = a + blin[k];
  }
}

extern "C" void kernel_launch(void* const* d_in, const int* in_sizes, int n_in,
                              void* d_out, int out_size, void* d_ws, size_t ws_size,
                              hipStream_t stream) {
  const float* x        = (const float*)d_in[0];
  const int*   ei       = (const int*)d_in[1];
  const int*   batch    = (const int*)d_in[2];
  const float* W1       = (const float*)d_in[3];
  const float* att_src1 = (const float*)d_in[4];
  const float* att_dst1 = (const float*)d_in[5];
  const float* b1       = (const float*)d_in[6];
  const float* W2       = (const float*)d_in[7];
  const float* att_src2 = (const float*)d_in[8];
  const float* att_dst2 = (const float*)d_in[9];
  const float* b2       = (const float*)d_in[10];
  const float* Wlin     = (const float*)d_in[11];
  const float* blin     = (const float*)d_in[12];
  float* out = (float*)d_out;
  char* ws = (char*)d_ws;

  // workspace layout (bytes) — ~93 MB total
  unsigned short* h1b = (unsigned short*)(ws + 0);  // 51,200,000
  float* as1   = (float*)(ws + 51200000);           // 3,200,000
  float* ad1   = (float*)(ws + 54400000);           // 3,200,000
  int* counts  = (int*)(ws + 57600000);             // 400,000
  int* offs    = (int*)(ws + 58000000);             // 400,004 (+pad)
  int* cursor  = (int*)(ws + 58400256);             // 400,000
  int* esrc    = (int*)(ws + 58800256);             // 6,400,000
  int* bsums   = (int*)(ws + 65200256);             // 1,564 (+pad)
  float* sums  = (float*)(ws + 65202048);           // 8,192
  float* cnts  = (float*)(ws + 65210240);           // 256
  float* h2    = (float*)(ws + 65210496);           // 12,800,000
  float* as2   = (float*)(ws + 78010496);           // 400,000
  float* ad2   = (float*)(ws + 78410496);           // 400,000
  float* h3    = (float*)(ws + 78810496);           // 12,800,000

  const int nb_scan = (NN + 255) / 256;  // 391

  k_zero<<<nb_scan, 256, 0, stream>>>((unsigned int*)counts, NN);

  k_gemm1<<<(NN + 63) / 64, 256, 0, stream>>>(x, W1, att_src1, att_dst1, h1b, as1, ad1);

  k_count<<<(EE + 255) / 256, 256, 0, stream>>>(ei, counts);
  k_scan1<<<nb_scan, 256, 0, stream>>>(counts, offs, bsums);
  k_scan2<<<1, 512, 0, stream>>>(bsums, nb_scan);
  k_scan3<<<nb_scan, 256, 0, stream>>>(offs, bsums, cursor);
  k_scatter<<<(EE + 255) / 256, 256, 0, stream>>>(ei, cursor, esrc);

  k_agg1<<<NN, 128, 0, stream>>>(h1b, as1, ad1, offs, esrc, b1, W2,
                                 att_src2, att_dst2, h2, as2, ad2);

  k_agg2<<<NN / 8, 256, 0, stream>>>(h2, as2, ad2, offs, esrc, b2, h3);
  k_pool<<<GG, 256, 0, stream>>>(h3, batch, sums, cnts);

  k_final<<<1, 640, 0, stream>>>(sums, cnts, Wlin, blin, out);
}

// Round 5
// 784.042 us; speedup vs baseline: 1.3686x; 1.0063x over previous
//
#include <hip/hip_runtime.h>
#include <cstdint>

#define NN 100000
#define EE 1600000
#define GG 64
#define FIN 128
#define HC 256      // H*C for layer 1
#define NC 10

static __device__ __forceinline__ float lrelu(float x) { return x > 0.f ? x : 0.2f * x; }
static __device__ __forceinline__ float bf2f(unsigned short b) {
  return __uint_as_float(((unsigned int)b) << 16);
}
static __device__ __forceinline__ unsigned short f2bf(float f) {
  unsigned int u = __float_as_uint(f);
  unsigned int r = (u + 0x7FFFu + ((u >> 16) & 1u)) >> 16;
  return (unsigned short)r;
}
static __device__ __forceinline__ void unpack2(unsigned int u, float& f0, float& f1) {
  f0 = __uint_as_float(u << 16);          // even channel (lo ushort)
  f1 = __uint_as_float(u & 0xFFFF0000u);  // odd channel (hi ushort)
}

// ---------------- utility ----------------
__global__ void k_zero(unsigned int* __restrict__ p, int n) {
  int i = blockIdx.x * 256 + threadIdx.x;
  if (i < n) p[i] = 0u;
}

// ---------------- GEMM1 + fused scores1 ----------------
__global__ __launch_bounds__(256) void k_gemm1(const float* __restrict__ x,
                                               const float* __restrict__ W1,
                                               const float* __restrict__ att_src1,
                                               const float* __restrict__ att_dst1,
                                               unsigned short* __restrict__ h1b,
                                               float* __restrict__ as1,
                                               float* __restrict__ ad1) {
  __shared__ float As[8][64];
  __shared__ float Bs[8][256];
  const int t = threadIdx.x;
  const int m0 = blockIdx.x * 64;
  const int tx = t & 15;
  const int ty = t >> 4;
  float4 acc[4][4];
#pragma unroll
  for (int j = 0; j < 4; ++j)
#pragma unroll
    for (int r = 0; r < 4; ++r) acc[j][r] = make_float4(0.f, 0.f, 0.f, 0.f);

  for (int k0 = 0; k0 < FIN; k0 += 8) {
    __syncthreads();
    if (t < 128) {
      int m = t >> 1;
      int kk = (t & 1) * 4;
      int row = m0 + m; if (row >= NN) row = NN - 1;
      const float4 xv = *(const float4*)(x + row * FIN + k0 + kk);
      As[kk + 0][m] = xv.x; As[kk + 1][m] = xv.y;
      As[kk + 2][m] = xv.z; As[kk + 3][m] = xv.w;
    }
#pragma unroll
    for (int i = 0; i < 8; ++i) Bs[i][t] = W1[(k0 + i) * HC + t];
    __syncthreads();
#pragma unroll
    for (int k = 0; k < 8; ++k) {
      const float4 a4 = *(const float4*)&As[k][ty * 4];
      const float ar[4] = {a4.x, a4.y, a4.z, a4.w};
#pragma unroll
      for (int j = 0; j < 4; ++j) {
        const float4 b4 = *(const float4*)&Bs[k][tx * 4 + 64 * j];
#pragma unroll
        for (int r = 0; r < 4; ++r) {
          acc[j][r].x += ar[r] * b4.x; acc[j][r].y += ar[r] * b4.y;
          acc[j][r].z += ar[r] * b4.z; acc[j][r].w += ar[r] * b4.w;
        }
      }
    }
  }
  // epilogue: bf16 store + fused attention scores
  const int txl = tx & 7;
  const int hsel = tx >> 3;
  float4 avs[4], avd[4];
#pragma unroll
  for (int j = 0; j < 4; ++j) {
    int h = 2 * j + hsel;
    avs[j] = *(const float4*)(att_src1 + h * 32 + txl * 4);
    avd[j] = *(const float4*)(att_dst1 + h * 32 + txl * 4);
  }
#pragma unroll
  for (int r = 0; r < 4; ++r) {
    int row = m0 + ty * 4 + r;
    bool ok = row < NN;
#pragma unroll
    for (int j = 0; j < 4; ++j) {
      float4 a = acc[j][r];
      if (ok) {
        ushort4 u;
        u.x = f2bf(a.x); u.y = f2bf(a.y); u.z = f2bf(a.z); u.w = f2bf(a.w);
        *(ushort4*)(h1b + (size_t)row * HC + tx * 4 + 64 * j) = u;
      }
      float vs = a.x * avs[j].x + a.y * avs[j].y + a.z * avs[j].z + a.w * avs[j].w;
      float vd = a.x * avd[j].x + a.y * avd[j].y + a.z * avd[j].z + a.w * avd[j].w;
      vs += __shfl_xor(vs, 1, 64); vs += __shfl_xor(vs, 2, 64); vs += __shfl_xor(vs, 4, 64);
      vd += __shfl_xor(vd, 1, 64); vd += __shfl_xor(vd, 2, 64); vd += __shfl_xor(vd, 4, 64);
      if (ok && txl == 0) {
        as1[row * 8 + 2 * j + hsel] = vs;
        ad1[row * 8 + 2 * j + hsel] = vd;
      }
    }
  }
}

// ---------------- CSR build ----------------
__global__ void k_count(const int* __restrict__ ei, int* __restrict__ counts) {
  int e = blockIdx.x * 256 + threadIdx.x;
  if (e < EE) atomicAdd(&counts[ei[EE + e]], 1);
}

__global__ void k_scan1(const int* __restrict__ counts, int* __restrict__ offs,
                        int* __restrict__ bsums) {
  __shared__ int s[256];
  const int t = threadIdx.x;
  const int i = blockIdx.x * 256 + t;
  int v = (i < NN) ? counts[i] : 0;
  s[t] = v;
  __syncthreads();
  for (int off = 1; off < 256; off <<= 1) {
    int tv = (t >= off) ? s[t - off] : 0;
    __syncthreads();
    s[t] += tv;
    __syncthreads();
  }
  if (i < NN) offs[i] = s[t] - v;
  if (t == 255) bsums[blockIdx.x] = s[255];
}

__global__ void k_scan2(int* __restrict__ bsums, int nb) {
  __shared__ int s[512];
  const int t = threadIdx.x;
  int v = (t < nb) ? bsums[t] : 0;
  s[t] = v;
  __syncthreads();
  for (int off = 1; off < 512; off <<= 1) {
    int tv = (t >= off) ? s[t - off] : 0;
    __syncthreads();
    s[t] += tv;
    __syncthreads();
  }
  if (t < nb) bsums[t] = s[t] - v;
}

__global__ void k_scan3(int* __restrict__ offs, const int* __restrict__ bsums,
                        int* __restrict__ cursor) {
  const int i = blockIdx.x * 256 + threadIdx.x;
  if (i < NN) {
    int v = offs[i] + bsums[i >> 8];
    offs[i] = v;
    cursor[i] = v;
  }
  if (i == 0) offs[NN] = EE;
}

__global__ void k_scatter(const int* __restrict__ ei, int* __restrict__ cursor,
                          int* __restrict__ esrc) {
  int e = blockIdx.x * 256 + threadIdx.x;
  if (e < EE) {
    int d = ei[EE + e];
    int p = atomicAdd(&cursor[d], 1);
    esrc[p] = ei[e];
  }
}

// ---------------- fused agg1 + bias + ELU + GEMM2 row + scores2 ----------------
// 128 threads per node; thread t owns channel pair (2t, 2t+1); head = t>>4.
// esrc chunk in registers (both waves redundantly hold edges 0..31 in lanes
// l&31); row index broadcast via readlane (uniform j2 -> SGPR row base).
__global__ __launch_bounds__(128) void k_agg1(const unsigned short* __restrict__ h1b,
                                              const float* __restrict__ as1,
                                              const float* __restrict__ ad1,
                                              const int* __restrict__ offs,
                                              const int* __restrict__ esrc,
                                              const float* __restrict__ b1,
                                              const float* __restrict__ W2,
                                              const float* __restrict__ att_src2,
                                              const float* __restrict__ att_dst2,
                                              unsigned short* __restrict__ h2b,
                                              float* __restrict__ as2,
                                              float* __restrict__ ad2) {
  __shared__ float wl[32][8];
  __shared__ float adl[8];
  __shared__ float sv[256];
  __shared__ float sp[4][33];
  const int n = blockIdx.x;
  const int t = threadIdx.x;      // 0..127
  const int head = t >> 4;        // 0..7
  const int start = offs[n], end = offs[n + 1];
  if (t < 8) adl[t] = ad1[n * 8 + t];
  __syncthreads();
  const float ad = adl[head];
  const unsigned int* h1u = (const unsigned int*)h1b;

  float w0 = __expf(lrelu(as1[n * 8 + head] + ad));
  float z = w0;
  float f0, f1;
  unpack2(h1u[(size_t)n * 128 + t], f0, f1);
  float acc0 = w0 * f0, acc1 = w0 * f1;

  for (int base = start; base < end; base += 32) {
    const int cnt = min(32, end - base);
    int s_reg = 0;
    {
      const int lane = t & 31;
      if (lane < cnt) s_reg = esrc[base + lane];
    }
    __syncthreads();  // wl reuse protection (prev chunk readers done)
    {
      const int j = t >> 2;           // 0..31 across the block (0..15 w0, 16..31 w1)
      const int hh = (t & 3) * 2;
      int sj = __shfl(s_reg, j & 31, 64);  // all lanes execute; src lane j holds edge j
      if (j < cnt) {
        float2 av = *(const float2*)(as1 + sj * 8 + hh);
        wl[j][hh]     = __expf(lrelu(av.x + adl[hh]));
        wl[j][hh + 1] = __expf(lrelu(av.y + adl[hh + 1]));
      }
    }
    __syncthreads();
#pragma unroll 8
    for (int j2 = 0; j2 < cnt; ++j2) {
      int sj = __builtin_amdgcn_readlane(s_reg, j2);   // uniform -> SGPR
      const unsigned int* row = h1u + (size_t)sj * 128; // scalar base
      float g0, g1;
      unpack2(row[t], g0, g1);
      float w2 = wl[j2][head];
      z += w2;
      acc0 += w2 * g0;
      acc1 += w2 * g1;
    }
  }
  const float zi = 1.0f / (z + 1e-16f);
  const float2 bb = *(const float2*)(b1 + 2 * t);
  float v0 = acc0 * zi + bb.x;
  float v1 = acc1 * zi + bb.y;
  v0 = v0 > 0.f ? v0 : (__expf(v0) - 1.0f);
  v1 = v1 > 0.f ? v1 : (__expf(v1) - 1.0f);
  *(float2*)(sv + 2 * t) = make_float2(v0, v1);
  __syncthreads();
  // GEMM2 row: 4 k-slices of 64, c = output channel
  const int c = t & 31, rr = t >> 5;
  const float* svp = sv + rr * 64;
  const float* w2p = W2 + rr * 64 * 32 + c;
  float p = 0.f;
#pragma unroll 16
  for (int kk = 0; kk < 64; ++kk) p += svp[kk] * w2p[kk * 32];
  sp[rr][c] = p;
  __syncthreads();
  if (t < 32) {
    float hv = sp[0][t] + sp[1][t] + sp[2][t] + sp[3][t];
    h2b[(size_t)n * 32 + t] = f2bf(hv);
    float ps = hv * att_src2[t];
    float pd = hv * att_dst2[t];
#pragma unroll
    for (int m = 16; m >= 1; m >>= 1) {
      ps += __shfl_xor(ps, m, 64);
      pd += __shfl_xor(pd, m, 64);
    }
    if (t == 0) { as2[n] = ps; ad2[n] = pd; }
  }
}

// ---------------- agg2: softmax-weighted sum -> dense h3 (bf16 gather) ----------------
__global__ __launch_bounds__(256) void k_agg2(const unsigned short* __restrict__ h2b,
                                              const float* __restrict__ as2,
                                              const float* __restrict__ ad2,
                                              const int* __restrict__ offs,
                                              const int* __restrict__ esrc,
                                              const float* __restrict__ b2,
                                              float* __restrict__ h3) {
  const int t = threadIdx.x;
  const int g = t >> 5, c = t & 31;
  const int n = blockIdx.x * 8 + g;
  const int sbase = t & 32;
  const int start = offs[n], end = offs[n + 1];
  const float adn = ad2[n];
  float w0 = __expf(lrelu(as2[n] + adn));
  float z = w0;
  float acc = w0 * bf2f(h2b[(size_t)n * 32 + c]);
  for (int base = start; base < end; base += 32) {
    const int cnt = min(32, end - base);
    int s_reg = 0; float w_reg = 0.f;
    if (c < cnt) {
      s_reg = esrc[base + c];
      w_reg = __expf(lrelu(as2[s_reg] + adn));
    }
#pragma unroll 8
    for (int j = 0; j < cnt; ++j) {
      int sj = __shfl(s_reg, sbase + j, 64);
      float wj = __shfl(w_reg, sbase + j, 64);
      z += wj;
      acc += wj * bf2f(h2b[(size_t)sj * 32 + c]);
    }
  }
  h3[(size_t)n * 32 + c] = acc / (z + 1e-16f) + b2[c];
}

// ---------------- pool: atomic-free segment mean via binary search ----------------
__global__ __launch_bounds__(256) void k_pool(const float* __restrict__ h3,
                                              const int* __restrict__ batch,
                                              float* __restrict__ sums,
                                              float* __restrict__ cnts) {
  __shared__ int bounds[2];
  __shared__ float red[8][33];
  const int g = blockIdx.x;
  const int t = threadIdx.x;
  if (t < 2) {
    int target = g + t;
    int lo = 0, hi = NN;
    while (lo < hi) { int mid = (lo + hi) >> 1; if (batch[mid] < target) lo = mid + 1; else hi = mid; }
    bounds[t] = lo;
  }
  __syncthreads();
  const int lo = bounds[0], hi = bounds[1];
  const int rr = t >> 5, c = t & 31;
  float a = 0.f;
  for (int r = lo + rr; r < hi; r += 8) a += h3[(size_t)r * 32 + c];
  red[rr][c] = a;
  __syncthreads();
  if (rr == 0) {
    float s = 0.f;
#pragma unroll
    for (int i = 0; i < 8; ++i) s += red[i][c];
    sums[g * 32 + c] = s;
    if (c == 0) cnts[g] = (float)(hi - lo);
  }
}

// ---------------- final ----------------
__global__ void k_final(const float* __restrict__ sums, const float* __restrict__ cnts,
                        const float* __restrict__ Wlin, const float* __restrict__ blin,
                        float* __restrict__ out) {
  const int t = threadIdx.x;
  if (t < GG * NC) {
    int g = t / NC, k = t % NC;
    float cnt = cnts[g];
    cnt = cnt > 1.f ? cnt : 1.f;
    float a = 0.f;
#pragma unroll
    for (int c = 0; c < 32; ++c) a += (sums[g * 32 + c] / cnt) * Wlin[c * NC + k];
    out[t] = a + blin[k];
  }
}

extern "C" void kernel_launch(void* const* d_in, const int* in_sizes, int n_in,
                              void* d_out, int out_size, void* d_ws, size_t ws_size,
                              hipStream_t stream) {
  const float* x        = (const float*)d_in[0];
  const int*   ei       = (const int*)d_in[1];
  const int*   batch    = (const int*)d_in[2];
  const float* W1       = (const float*)d_in[3];
  const float* att_src1 = (const float*)d_in[4];
  const float* att_dst1 = (const float*)d_in[5];
  const float* b1       = (const float*)d_in[6];
  const float* W2       = (const float*)d_in[7];
  const float* att_src2 = (const float*)d_in[8];
  const float* att_dst2 = (const float*)d_in[9];
  const float* b2       = (const float*)d_in[10];
  const float* Wlin     = (const float*)d_in[11];
  const float* blin     = (const float*)d_in[12];
  float* out = (float*)d_out;
  char* ws = (char*)d_ws;

  // workspace layout (bytes)
  unsigned short* h1b = (unsigned short*)(ws + 0);  // 51,200,000
  float* as1   = (float*)(ws + 51200000);           // 3,200,000
  float* ad1   = (float*)(ws + 54400000);           // 3,200,000
  int* counts  = (int*)(ws + 57600000);             // 400,000
  int* offs    = (int*)(ws + 58000000);             // 400,004 (+pad)
  int* cursor  = (int*)(ws + 58400256);             // 400,000
  int* esrc    = (int*)(ws + 58800256);             // 6,400,000
  int* bsums   = (int*)(ws + 65200256);             // 1,564 (+pad)
  float* sums  = (float*)(ws + 65202048);           // 8,192
  float* cnts  = (float*)(ws + 65210240);           // 256
  unsigned short* h2b = (unsigned short*)(ws + 65210496); // 6,400,000
  float* as2   = (float*)(ws + 71610496);           // 400,000
  float* ad2   = (float*)(ws + 72010496);           // 400,000
  float* h3    = (float*)(ws + 72410496);           // 12,800,000

  const int nb_scan = (NN + 255) / 256;  // 391

  k_zero<<<nb_scan, 256, 0, stream>>>((unsigned int*)counts, NN);

  k_gemm1<<<(NN + 63) / 64, 256, 0, stream>>>(x, W1, att_src1, att_dst1, h1b, as1, ad1);

  k_count<<<(EE + 255) / 256, 256, 0, stream>>>(ei, counts);
  k_scan1<<<nb_scan, 256, 0, stream>>>(counts, offs, bsums);
  k_scan2<<<1, 512, 0, stream>>>(bsums, nb_scan);
  k_scan3<<<nb_scan, 256, 0, stream>>>(offs, bsums, cursor);
  k_scatter<<<(EE + 255) / 256, 256, 0, stream>>>(ei, cursor, esrc);

  k_agg1<<<NN, 128, 0, stream>>>(h1b, as1, ad1, offs, esrc, b1, W2,
                                 att_src2, att_dst2, h2b, as2, ad2);

  k_agg2<<<NN / 8, 256, 0, stream>>>(h2b, as2, ad2, offs, esrc, b2, h3);
  k_pool<<<GG, 256, 0, stream>>>(h3, batch, sums, cnts);

  k_final<<<1, 640, 0, stream>>>(sums, cnts, Wlin, blin, out);
}

// Round 6
// 737.880 us; speedup vs baseline: 1.4542x; 1.0626x over previous
//
#include <hip/hip_runtime.h>
#include <cstdint>

#define NN 100000
#define EE 1600000
#define GG 64
#define FIN 128
#define HC 256      // H*C for layer 1
#define NC 10

typedef short v8s __attribute__((ext_vector_type(8)));
typedef float v4f __attribute__((ext_vector_type(4)));

static __device__ __forceinline__ float lrelu(float x) { return x > 0.f ? x : 0.2f * x; }
static __device__ __forceinline__ float bf2f(unsigned short b) {
  return __uint_as_float(((unsigned int)b) << 16);
}
static __device__ __forceinline__ unsigned short f2bf(float f) {
  unsigned int u = __float_as_uint(f);
  unsigned int r = (u + 0x7FFFu + ((u >> 16) & 1u)) >> 16;
  return (unsigned short)r;
}
static __device__ __forceinline__ void unpack2(unsigned int u, float& f0, float& f1) {
  f0 = __uint_as_float(u << 16);          // even channel (lo ushort)
  f1 = __uint_as_float(u & 0xFFFF0000u);  // odd channel (hi ushort)
}

// ---------------- utility ----------------
__global__ void k_zero(unsigned int* __restrict__ p, int n) {
  int i = blockIdx.x * 256 + threadIdx.x;
  if (i < n) p[i] = 0u;
}

// ---------------- GEMM1 (bf16 MFMA): h1b = bf16(x) @ bf16(W1) ----------------
// grid (1563, 2): 64 rows x 128-col half per block; 4 waves x 16 rows.
// W1 half staged in LDS transposed [n][k], stride 144 halfs (16B-aligned rows).
__global__ __launch_bounds__(256) void k_gemm1(const float* __restrict__ x,
                                               const float* __restrict__ W1,
                                               unsigned short* __restrict__ h1b) {
  __shared__ short W1t[128 * 144];
  const int t = threadIdx.x;
  const int m0 = blockIdx.x * 64;
  const int n0 = blockIdx.y * 128;
  {
    const int n4 = (t & 31) * 4;
    const int kb = t >> 5;               // 0..7
#pragma unroll
    for (int pass = 0; pass < 16; ++pass) {
      int k = pass * 8 + kb;
      float4 v = *(const float4*)(W1 + k * HC + n0 + n4);
      W1t[(n4 + 0) * 144 + k] = (short)f2bf(v.x);
      W1t[(n4 + 1) * 144 + k] = (short)f2bf(v.y);
      W1t[(n4 + 2) * 144 + k] = (short)f2bf(v.z);
      W1t[(n4 + 3) * 144 + k] = (short)f2bf(v.w);
    }
  }
  __syncthreads();
  const int lane = t & 63;
  const int wm = t >> 6;                 // wave -> m sub-tile
  const int ml = lane & 15;
  const int quad = lane >> 4;
  int row = m0 + wm * 16 + ml; if (row >= NN) row = NN - 1;
  v4f acc[8];
#pragma unroll
  for (int tt = 0; tt < 8; ++tt) acc[tt] = (v4f){0.f, 0.f, 0.f, 0.f};
#pragma unroll
  for (int kk = 0; kk < 4; ++kk) {
    const int k0 = kk * 32 + quad * 8;
    float4 lo = *(const float4*)(x + (size_t)row * FIN + k0);
    float4 hi = *(const float4*)(x + (size_t)row * FIN + k0 + 4);
    v8s a;
    a[0] = (short)f2bf(lo.x); a[1] = (short)f2bf(lo.y);
    a[2] = (short)f2bf(lo.z); a[3] = (short)f2bf(lo.w);
    a[4] = (short)f2bf(hi.x); a[5] = (short)f2bf(hi.y);
    a[6] = (short)f2bf(hi.z); a[7] = (short)f2bf(hi.w);
#pragma unroll
    for (int tt = 0; tt < 8; ++tt) {
      v8s b = *(const v8s*)&W1t[(tt * 16 + ml) * 144 + k0];
      acc[tt] = __builtin_amdgcn_mfma_f32_16x16x32_bf16(a, b, acc[tt], 0, 0, 0);
    }
  }
#pragma unroll
  for (int tt = 0; tt < 8; ++tt) {
#pragma unroll
    for (int r = 0; r < 4; ++r) {
      int rg = m0 + wm * 16 + quad * 4 + r;
      if (rg < NN) h1b[(size_t)rg * HC + n0 + tt * 16 + ml] = f2bf(acc[tt][r]);
    }
  }
}

// ---------------- scores1 from bf16 h1 ----------------
__global__ __launch_bounds__(256) void k_scores1(const unsigned short* __restrict__ h1,
                                                 const float* __restrict__ att_src,
                                                 const float* __restrict__ att_dst,
                                                 float* __restrict__ as1,
                                                 float* __restrict__ ad1) {
  __shared__ float sa[8 * 33], sd[8 * 33];
  const int t = threadIdx.x;
  {
    int hh = t >> 5, cc = t & 31;
    sa[hh * 33 + cc] = att_src[t];
    sd[hh * 33 + cc] = att_dst[t];
  }
  __syncthreads();
  const int idx = blockIdx.x * 256 + t;
  const int head = idx & 7;
  const uint4* p = (const uint4*)(h1 + (size_t)(idx >> 3) * HC + head * 32);
  const float* sap = &sa[head * 33];
  const float* sdp = &sd[head * 33];
  float s_acc = 0.f, d_acc = 0.f;
#pragma unroll
  for (int q = 0; q < 4; ++q) {
    uint4 u4 = p[q];
    unsigned int uu[4] = {u4.x, u4.y, u4.z, u4.w};
#pragma unroll
    for (int i = 0; i < 4; ++i) {
      float f0, f1; unpack2(uu[i], f0, f1);
      int c = q * 8 + i * 2;
      s_acc += f0 * sap[c] + f1 * sap[c + 1];
      d_acc += f0 * sdp[c] + f1 * sdp[c + 1];
    }
  }
  as1[idx] = s_acc;
  ad1[idx] = d_acc;
}

// ---------------- CSR build ----------------
__global__ void k_count(const int* __restrict__ ei, int* __restrict__ counts) {
  int e = blockIdx.x * 256 + threadIdx.x;
  if (e < EE) atomicAdd(&counts[ei[EE + e]], 1);
}

__global__ void k_scan1(const int* __restrict__ counts, int* __restrict__ offs,
                        int* __restrict__ bsums) {
  __shared__ int s[256];
  const int t = threadIdx.x;
  const int i = blockIdx.x * 256 + t;
  int v = (i < NN) ? counts[i] : 0;
  s[t] = v;
  __syncthreads();
  for (int off = 1; off < 256; off <<= 1) {
    int tv = (t >= off) ? s[t - off] : 0;
    __syncthreads();
    s[t] += tv;
    __syncthreads();
  }
  if (i < NN) offs[i] = s[t] - v;
  if (t == 255) bsums[blockIdx.x] = s[255];
}

__global__ void k_scan2(int* __restrict__ bsums, int nb) {
  __shared__ int s[512];
  const int t = threadIdx.x;
  int v = (t < nb) ? bsums[t] : 0;
  s[t] = v;
  __syncthreads();
  for (int off = 1; off < 512; off <<= 1) {
    int tv = (t >= off) ? s[t - off] : 0;
    __syncthreads();
    s[t] += tv;
    __syncthreads();
  }
  if (t < nb) bsums[t] = s[t] - v;
}

__global__ void k_scan3(int* __restrict__ offs, const int* __restrict__ bsums,
                        int* __restrict__ cursor) {
  const int i = blockIdx.x * 256 + threadIdx.x;
  if (i < NN) {
    int v = offs[i] + bsums[i >> 8];
    offs[i] = v;
    cursor[i] = v;
  }
  if (i == 0) offs[NN] = EE;
}

__global__ void k_scatter(const int* __restrict__ ei, int* __restrict__ cursor,
                          int* __restrict__ esrc, int* __restrict__ edst) {
  int e = blockIdx.x * 256 + threadIdx.x;
  if (e < EE) {
    int d = ei[EE + e];
    int p = atomicAdd(&cursor[d], 1);
    esrc[p] = ei[e];
    edst[p] = d;
  }
}

// ---------------- edge weights (layer 1), edge-parallel ----------------
// wt[slot][8] = exp(lrelu(as1[src]+ad1[dst])) ; 2 threads/edge x 4 heads.
__global__ __launch_bounds__(256) void k_ew(const int* __restrict__ esrc,
                                            const int* __restrict__ edst,
                                            const float* __restrict__ as1,
                                            const float* __restrict__ ad1,
                                            float* __restrict__ wt) {
  int gid = blockIdx.x * 256 + threadIdx.x;
  int e = gid >> 1;
  int hh = (gid & 1) * 4;
  if (e < EE) {
    int s = esrc[e], d = edst[e];
    float4 a = *(const float4*)(as1 + s * 8 + hh);
    float4 b = *(const float4*)(ad1 + d * 8 + hh);
    float4 r;
    r.x = __expf(lrelu(a.x + b.x));
    r.y = __expf(lrelu(a.y + b.y));
    r.z = __expf(lrelu(a.z + b.z));
    r.w = __expf(lrelu(a.w + b.w));
    *(float4*)(wt + (size_t)e * 8 + hh) = r;
  }
}

// ---------------- fused agg1 + bias + ELU + GEMM2 row + scores2 ----------------
// 128 threads (2 waves) per node. Gather: each wave reads FULL 512B rows
// (64 lanes x uint2); waves split edges even/odd. Weights precomputed (wt).
__global__ __launch_bounds__(128) void k_agg1(const unsigned short* __restrict__ h1b,
                                              const float* __restrict__ as1,
                                              const float* __restrict__ ad1,
                                              const int* __restrict__ offs,
                                              const int* __restrict__ esrc,
                                              const float* __restrict__ wt,
                                              const float* __restrict__ b1,
                                              const float* __restrict__ W2,
                                              const float* __restrict__ att_src2,
                                              const float* __restrict__ att_dst2,
                                              unsigned short* __restrict__ h2b,
                                              float* __restrict__ as2,
                                              float* __restrict__ ad2) {
  __shared__ float wl[32][8];
  __shared__ float sv[256];
  __shared__ float zsh[2][8];
  __shared__ float sp[4][33];
  const int n = blockIdx.x;
  const int t = threadIdx.x;
  const int lane = t & 63;
  const int w = t >> 6;
  const int head = lane >> 3;          // channels 4*lane.. are in head lane>>3
  const int start = offs[n], end = offs[n + 1];
  const uint2* h1u2 = (const uint2*)h1b;

  float acc0 = 0.f, acc1 = 0.f, acc2 = 0.f, acc3 = 0.f, z = 0.f;
  if (w == 0) {   // self loop handled by wave 0
    float w0 = __expf(lrelu(as1[n * 8 + head] + ad1[n * 8 + head]));
    z = w0;
    uint2 q = h1u2[(size_t)n * 64 + lane];
    float f0, f1, f2, f3; unpack2(q.x, f0, f1); unpack2(q.y, f2, f3);
    acc0 = w0 * f0; acc1 = w0 * f1; acc2 = w0 * f2; acc3 = w0 * f3;
  }

  for (int base = start; base < end; base += 32) {
    const int cnt = min(32, end - base);
    int s_reg = 0;
    if (lane < cnt) s_reg = esrc[base + lane];
    __syncthreads();   // protect wl from previous chunk's readers
    {
      const int j = t >> 2, hh = (t & 3) * 2;
      if (j < cnt) *(float2*)&wl[j][hh] = *(const float2*)(wt + (size_t)(base + j) * 8 + hh);
    }
    __syncthreads();
#pragma unroll 4
    for (int j2 = w; j2 < cnt; j2 += 2) {
      int sj = __builtin_amdgcn_readlane(s_reg, j2);   // uniform -> SGPR base
      uint2 q = h1u2[(size_t)sj * 64 + lane];          // full row per wave
      float wv = wl[j2][head];
      float f0, f1, f2, f3; unpack2(q.x, f0, f1); unpack2(q.y, f2, f3);
      z += wv;
      acc0 += wv * f0; acc1 += wv * f1; acc2 += wv * f2; acc3 += wv * f3;
    }
  }

  __syncthreads();
  if (w == 0) {
    *(float4*)&sv[4 * lane] = make_float4(acc0, acc1, acc2, acc3);
    if ((lane & 7) == 0) zsh[0][head] = z;
  }
  __syncthreads();
  if (w == 1) {
    float4 p = *(float4*)&sv[4 * lane];
    p.x += acc0; p.y += acc1; p.z += acc2; p.w += acc3;
    *(float4*)&sv[4 * lane] = p;
    if ((lane & 7) == 0) zsh[1][head] = z;
  }
  __syncthreads();
  {  // out1 = sv/z + b1, ELU (thread t -> channels 2t, 2t+1)
    const int ho = t >> 4;
    const float zf = zsh[0][ho] + zsh[1][ho];
    const float zi = 1.0f / (zf + 1e-16f);
    float2 bb = *(const float2*)(b1 + 2 * t);
    float v0 = sv[2 * t] * zi + bb.x;
    float v1 = sv[2 * t + 1] * zi + bb.y;
    v0 = v0 > 0.f ? v0 : (__expf(v0) - 1.0f);
    v1 = v1 > 0.f ? v1 : (__expf(v1) - 1.0f);
    __syncthreads();
    sv[2 * t] = v0; sv[2 * t + 1] = v1;
  }
  __syncthreads();
  // GEMM2 row: 4 k-slices of 64, c = output channel
  const int c = t & 31, rr = t >> 5;
  const float* svp = sv + rr * 64;
  const float* w2p = W2 + rr * 64 * 32 + c;
  float p = 0.f;
#pragma unroll 16
  for (int kk = 0; kk < 64; ++kk) p += svp[kk] * w2p[kk * 32];
  sp[rr][c] = p;
  __syncthreads();
  if (t < 32) {
    float hv = sp[0][t] + sp[1][t] + sp[2][t] + sp[3][t];
    h2b[(size_t)n * 32 + t] = f2bf(hv);
    float ps = hv * att_src2[t];
    float pd = hv * att_dst2[t];
#pragma unroll
    for (int m = 16; m >= 1; m >>= 1) {
      ps += __shfl_xor(ps, m, 64);
      pd += __shfl_xor(pd, m, 64);
    }
    if (t == 0) { as2[n] = ps; ad2[n] = pd; }
  }
}

// ---------------- agg2: softmax-weighted sum -> dense h3 ----------------
__global__ __launch_bounds__(256) void k_agg2(const unsigned short* __restrict__ h2b,
                                              const float* __restrict__ as2,
                                              const float* __restrict__ ad2,
                                              const int* __restrict__ offs,
                                              const int* __restrict__ esrc,
                                              const float* __restrict__ b2,
                                              float* __restrict__ h3) {
  const int t = threadIdx.x;
  const int g = t >> 5, c = t & 31;
  const int n = blockIdx.x * 8 + g;
  const int sbase = t & 32;
  const int start = offs[n], end = offs[n + 1];
  const float adn = ad2[n];
  float w0 = __expf(lrelu(as2[n] + adn));
  float z = w0;
  float acc = w0 * bf2f(h2b[(size_t)n * 32 + c]);
  for (int base = start; base < end; base += 32) {
    const int cnt = min(32, end - base);
    int s_reg = 0; float w_reg = 0.f;
    if (c < cnt) {
      s_reg = esrc[base + c];
      w_reg = __expf(lrelu(as2[s_reg] + adn));
    }
#pragma unroll 8
    for (int j = 0; j < cnt; ++j) {
      int sj = __shfl(s_reg, sbase + j, 64);
      float wj = __shfl(w_reg, sbase + j, 64);
      z += wj;
      acc += wj * bf2f(h2b[(size_t)sj * 32 + c]);
    }
  }
  h3[(size_t)n * 32 + c] = acc / (z + 1e-16f) + b2[c];
}

// ---------------- pool ----------------
__global__ __launch_bounds__(256) void k_pool(const float* __restrict__ h3,
                                              const int* __restrict__ batch,
                                              float* __restrict__ sums,
                                              float* __restrict__ cnts) {
  __shared__ int bounds[2];
  __shared__ float red[8][33];
  const int g = blockIdx.x;
  const int t = threadIdx.x;
  if (t < 2) {
    int target = g + t;
    int lo = 0, hi = NN;
    while (lo < hi) { int mid = (lo + hi) >> 1; if (batch[mid] < target) lo = mid + 1; else hi = mid; }
    bounds[t] = lo;
  }
  __syncthreads();
  const int lo = bounds[0], hi = bounds[1];
  const int rr = t >> 5, c = t & 31;
  float a = 0.f;
  for (int r = lo + rr; r < hi; r += 8) a += h3[(size_t)r * 32 + c];
  red[rr][c] = a;
  __syncthreads();
  if (rr == 0) {
    float s = 0.f;
#pragma unroll
    for (int i = 0; i < 8; ++i) s += red[i][c];
    sums[g * 32 + c] = s;
    if (c == 0) cnts[g] = (float)(hi - lo);
  }
}

// ---------------- final ----------------
__global__ void k_final(const float* __restrict__ sums, const float* __restrict__ cnts,
                        const float* __restrict__ Wlin, const float* __restrict__ blin,
                        float* __restrict__ out) {
  const int t = threadIdx.x;
  if (t < GG * NC) {
    int g = t / NC, k = t % NC;
    float cnt = cnts[g];
    cnt = cnt > 1.f ? cnt : 1.f;
    float a = 0.f;
#pragma unroll
    for (int c = 0; c < 32; ++c) a += (sums[g * 32 + c] / cnt) * Wlin[c * NC + k];
    out[t] = a + blin[k];
  }
}

extern "C" void kernel_launch(void* const* d_in, const int* in_sizes, int n_in,
                              void* d_out, int out_size, void* d_ws, size_t ws_size,
                              hipStream_t stream) {
  const float* x        = (const float*)d_in[0];
  const int*   ei       = (const int*)d_in[1];
  const int*   batch    = (const int*)d_in[2];
  const float* W1       = (const float*)d_in[3];
  const float* att_src1 = (const float*)d_in[4];
  const float* att_dst1 = (const float*)d_in[5];
  const float* b1       = (const float*)d_in[6];
  const float* W2       = (const float*)d_in[7];
  const float* att_src2 = (const float*)d_in[8];
  const float* att_dst2 = (const float*)d_in[9];
  const float* b2       = (const float*)d_in[10];
  const float* Wlin     = (const float*)d_in[11];
  const float* blin     = (const float*)d_in[12];
  float* out = (float*)d_out;
  char* ws = (char*)d_ws;

  // workspace layout (bytes); peak ~130 MB (wt/h3 overlaid: wt dead after agg1)
  unsigned short* h1b = (unsigned short*)(ws + 0);        // 51,200,000
  float* as1   = (float*)(ws + 51200000);                 // 3,200,000
  float* ad1   = (float*)(ws + 54400000);                 // 3,200,000
  int* counts  = (int*)(ws + 57600000);                   // 400,000
  int* offs    = (int*)(ws + 58000000);                   // 400,004 (+pad)
  int* cursor  = (int*)(ws + 58400256);                   // 400,000
  int* esrc    = (int*)(ws + 58800256);                   // 6,400,000
  int* edst    = (int*)(ws + 65200256);                   // 6,400,000
  int* bsums   = (int*)(ws + 71600256);                   // 1,564 (+pad)
  float* sums  = (float*)(ws + 71602048);                 // 8,192
  float* cnts  = (float*)(ws + 71610240);                 // 256
  unsigned short* h2b = (unsigned short*)(ws + 71610496); // 6,400,000
  float* as2   = (float*)(ws + 78010496);                 // 400,000
  float* ad2   = (float*)(ws + 78410496);                 // 400,000
  float* wt    = (float*)(ws + 78810496);                 // 51,200,000 (dead after agg1)
  float* h3    = (float*)(ws + 78810496);                 // 12,800,000 (overlaid)

  const int nb_scan = (NN + 255) / 256;  // 391

  k_zero<<<nb_scan, 256, 0, stream>>>((unsigned int*)counts, NN);

  dim3 g1((NN + 63) / 64, 2);
  k_gemm1<<<g1, 256, 0, stream>>>(x, W1, h1b);
  k_scores1<<<(NN * 8) / 256, 256, 0, stream>>>(h1b, att_src1, att_dst1, as1, ad1);

  k_count<<<(EE + 255) / 256, 256, 0, stream>>>(ei, counts);
  k_scan1<<<nb_scan, 256, 0, stream>>>(counts, offs, bsums);
  k_scan2<<<1, 512, 0, stream>>>(bsums, nb_scan);
  k_scan3<<<nb_scan, 256, 0, stream>>>(offs, bsums, cursor);
  k_scatter<<<(EE + 255) / 256, 256, 0, stream>>>(ei, cursor, esrc, edst);

  k_ew<<<(2 * EE) / 256, 256, 0, stream>>>(esrc, edst, as1, ad1, wt);

  k_agg1<<<NN, 128, 0, stream>>>(h1b, as1, ad1, offs, esrc, wt, b1, W2,
                                 att_src2, att_dst2, h2b, as2, ad2);

  k_agg2<<<NN / 8, 256, 0, stream>>>(h2b, as2, ad2, offs, esrc, b2, h3);
  k_pool<<<GG, 256, 0, stream>>>(h3, batch, sums, cnts);

  k_final<<<1, 640, 0, stream>>>(sums, cnts, Wlin, blin, out);
}

// Round 7
// 719.031 us; speedup vs baseline: 1.4923x; 1.0262x over previous
//
#include <hip/hip_runtime.h>
#include <cstdint>

#define NN 100000
#define EE 1600000
#define GG 64
#define FIN 128
#define HC 256      // H*C for layer 1
#define NC 10
#define WS 152      // W1t LDS stride in halfs: 8*WS B lane-delta == 16 mod 32 banks (free 2-way)

typedef short v8s __attribute__((ext_vector_type(8)));
typedef float v4f __attribute__((ext_vector_type(4)));

static __device__ __forceinline__ float lrelu(float x) { return x > 0.f ? x : 0.2f * x; }
static __device__ __forceinline__ float bf2f(unsigned short b) {
  return __uint_as_float(((unsigned int)b) << 16);
}
static __device__ __forceinline__ unsigned short f2bf(float f) {
  unsigned int u = __float_as_uint(f);
  unsigned int r = (u + 0x7FFFu + ((u >> 16) & 1u)) >> 16;
  return (unsigned short)r;
}
static __device__ __forceinline__ void unpack2(unsigned int u, float& f0, float& f1) {
  f0 = __uint_as_float(u << 16);          // even channel (lo ushort)
  f1 = __uint_as_float(u & 0xFFFF0000u);  // odd channel (hi ushort)
}

// ---------------- utility ----------------
__global__ void k_zero(unsigned int* __restrict__ p, int n) {
  int i = blockIdx.x * 256 + threadIdx.x;
  if (i < n) p[i] = 0u;
}

// ---------------- GEMM1 (bf16 MFMA) + fused scores1 ----------------
// grid (1563, 2): 64 rows x 128-col half per block; 4 waves x 16 rows.
// W1 half staged in LDS transposed [n][k], stride WS halfs.
// scores: per-head dot of fp32 accumulators with att vectors, ml-lane reduce.
__global__ __launch_bounds__(256) void k_gemm1(const float* __restrict__ x,
                                               const float* __restrict__ W1,
                                               const float* __restrict__ att_src1,
                                               const float* __restrict__ att_dst1,
                                               unsigned short* __restrict__ h1b,
                                               float* __restrict__ as1,
                                               float* __restrict__ ad1) {
  __shared__ short W1t[128 * WS];
  const int t = threadIdx.x;
  const int m0 = blockIdx.x * 64;
  const int n0 = blockIdx.y * 128;
  const int hb = blockIdx.y * 4;       // head base of this column half
  {
    const int n4 = (t & 31) * 4;
    const int kb = t >> 5;             // 0..7
#pragma unroll
    for (int pass = 0; pass < 16; ++pass) {
      int k = pass * 8 + kb;
      float4 v = *(const float4*)(W1 + k * HC + n0 + n4);
      W1t[(n4 + 0) * WS + k] = (short)f2bf(v.x);
      W1t[(n4 + 1) * WS + k] = (short)f2bf(v.y);
      W1t[(n4 + 2) * WS + k] = (short)f2bf(v.z);
      W1t[(n4 + 3) * WS + k] = (short)f2bf(v.w);
    }
  }
  __syncthreads();
  const int lane = t & 63;
  const int wm = t >> 6;               // wave -> m sub-tile
  const int ml = lane & 15;
  const int quad = lane >> 4;
  int row = m0 + wm * 16 + ml; if (row >= NN) row = NN - 1;
  v4f acc[8];
#pragma unroll
  for (int tt = 0; tt < 8; ++tt) acc[tt] = (v4f){0.f, 0.f, 0.f, 0.f};
#pragma unroll
  for (int kk = 0; kk < 4; ++kk) {
    const int k0 = kk * 32 + quad * 8;
    float4 lo = *(const float4*)(x + (size_t)row * FIN + k0);
    float4 hi = *(const float4*)(x + (size_t)row * FIN + k0 + 4);
    v8s a;
    a[0] = (short)f2bf(lo.x); a[1] = (short)f2bf(lo.y);
    a[2] = (short)f2bf(lo.z); a[3] = (short)f2bf(lo.w);
    a[4] = (short)f2bf(hi.x); a[5] = (short)f2bf(hi.y);
    a[6] = (short)f2bf(hi.z); a[7] = (short)f2bf(hi.w);
#pragma unroll
    for (int tt = 0; tt < 8; ++tt) {
      v8s b = *(const v8s*)&W1t[(tt * 16 + ml) * WS + k0];
      acc[tt] = __builtin_amdgcn_mfma_f32_16x16x32_bf16(a, b, acc[tt], 0, 0, 0);
    }
  }
  // h1b store (C layout: row=quad*4+r, col=tt*16+ml)
#pragma unroll
  for (int tt = 0; tt < 8; ++tt) {
#pragma unroll
    for (int r = 0; r < 4; ++r) {
      int rg = m0 + wm * 16 + quad * 4 + r;
      if (rg < NN) h1b[(size_t)rg * HC + n0 + tt * 16 + ml] = f2bf(acc[tt][r]);
    }
  }
  // fused scores1: 4 heads of this half; lane partials over its 8 columns
  float ps[4][4], pd[4][4];
#pragma unroll
  for (int i = 0; i < 4; ++i) {
#pragma unroll
    for (int r = 0; r < 4; ++r) { ps[i][r] = 0.f; pd[i][r] = 0.f; }
  }
#pragma unroll
  for (int i = 0; i < 4; ++i) {
#pragma unroll
    for (int half = 0; half < 2; ++half) {
      const int tt = 2 * i + half;
      const float a_s = att_src1[(hb + i) * 32 + half * 16 + ml];
      const float a_d = att_dst1[(hb + i) * 32 + half * 16 + ml];
#pragma unroll
      for (int r = 0; r < 4; ++r) {
        ps[i][r] += acc[tt][r] * a_s;
        pd[i][r] += acc[tt][r] * a_d;
      }
    }
  }
#pragma unroll
  for (int i = 0; i < 4; ++i) {
#pragma unroll
    for (int r = 0; r < 4; ++r) {
      float s = ps[i][r], d = pd[i][r];
      s += __shfl_xor(s, 1, 64); s += __shfl_xor(s, 2, 64);
      s += __shfl_xor(s, 4, 64); s += __shfl_xor(s, 8, 64);
      d += __shfl_xor(d, 1, 64); d += __shfl_xor(d, 2, 64);
      d += __shfl_xor(d, 4, 64); d += __shfl_xor(d, 8, 64);
      ps[i][r] = s; pd[i][r] = d;
    }
  }
  if (ml == 0) {
#pragma unroll
    for (int r = 0; r < 4; ++r) {
      int rg = m0 + wm * 16 + quad * 4 + r;
      if (rg < NN) {
#pragma unroll
        for (int i = 0; i < 4; ++i) {
          as1[rg * 8 + hb + i] = ps[i][r];
          ad1[rg * 8 + hb + i] = pd[i][r];
        }
      }
    }
  }
}

// ---------------- CSR build ----------------
__global__ void k_count(const int* __restrict__ ei, int* __restrict__ counts) {
  int e = blockIdx.x * 256 + threadIdx.x;
  if (e < EE) atomicAdd(&counts[ei[EE + e]], 1);
}

__global__ void k_scan1(const int* __restrict__ counts, int* __restrict__ offs,
                        int* __restrict__ bsums) {
  __shared__ int s[256];
  const int t = threadIdx.x;
  const int i = blockIdx.x * 256 + t;
  int v = (i < NN) ? counts[i] : 0;
  s[t] = v;
  __syncthreads();
  for (int off = 1; off < 256; off <<= 1) {
    int tv = (t >= off) ? s[t - off] : 0;
    __syncthreads();
    s[t] += tv;
    __syncthreads();
  }
  if (i < NN) offs[i] = s[t] - v;
  if (t == 255) bsums[blockIdx.x] = s[255];
}

__global__ void k_scan2(int* __restrict__ bsums, int nb) {
  __shared__ int s[512];
  const int t = threadIdx.x;
  int v = (t < nb) ? bsums[t] : 0;
  s[t] = v;
  __syncthreads();
  for (int off = 1; off < 512; off <<= 1) {
    int tv = (t >= off) ? s[t - off] : 0;
    __syncthreads();
    s[t] += tv;
    __syncthreads();
  }
  if (t < nb) bsums[t] = s[t] - v;
}

__global__ void k_scan3(int* __restrict__ offs, const int* __restrict__ bsums,
                        int* __restrict__ cursor) {
  const int i = blockIdx.x * 256 + threadIdx.x;
  if (i < NN) {
    int v = offs[i] + bsums[i >> 8];
    offs[i] = v;
    cursor[i] = v;
  }
  if (i == 0) offs[NN] = EE;
}

// ---------------- scatter + fused layer-1 edge weights ----------------
__global__ void k_scatter(const int* __restrict__ ei, int* __restrict__ cursor,
                          const float* __restrict__ as1, const float* __restrict__ ad1,
                          int* __restrict__ esrc, int* __restrict__ edst,
                          float* __restrict__ wt) {
  int e = blockIdx.x * 256 + threadIdx.x;
  if (e < EE) {
    int s = ei[e];
    int d = ei[EE + e];
    int p = atomicAdd(&cursor[d], 1);
    esrc[p] = s;
    edst[p] = d;
    float4 a0 = *(const float4*)(as1 + s * 8);
    float4 a1 = *(const float4*)(as1 + s * 8 + 4);
    float4 b0 = *(const float4*)(ad1 + d * 8);
    float4 b1 = *(const float4*)(ad1 + d * 8 + 4);
    float4 r0, r1;
    r0.x = __expf(lrelu(a0.x + b0.x)); r0.y = __expf(lrelu(a0.y + b0.y));
    r0.z = __expf(lrelu(a0.z + b0.z)); r0.w = __expf(lrelu(a0.w + b0.w));
    r1.x = __expf(lrelu(a1.x + b1.x)); r1.y = __expf(lrelu(a1.y + b1.y));
    r1.z = __expf(lrelu(a1.z + b1.z)); r1.w = __expf(lrelu(a1.w + b1.w));
    *(float4*)(wt + (size_t)p * 8) = r0;
    *(float4*)(wt + (size_t)p * 8 + 4) = r1;
  }
}

// ---------------- fused agg1 + bias + ELU + GEMM2 row + scores2 ----------------
// 128 threads (2 waves), TWO nodes per block, software-pipelined: both nodes'
// index chains (offs->esrc, wt) issued up front; gathers full 512B rows/wave.
__global__ __launch_bounds__(128) void k_agg1(const unsigned short* __restrict__ h1b,
                                              const float* __restrict__ as1,
                                              const float* __restrict__ ad1,
                                              const int* __restrict__ offs,
                                              const int* __restrict__ esrc,
                                              const float* __restrict__ wt,
                                              const float* __restrict__ b1,
                                              const float* __restrict__ W2,
                                              const float* __restrict__ att_src2,
                                              const float* __restrict__ att_dst2,
                                              unsigned short* __restrict__ h2b,
                                              float* __restrict__ as2,
                                              float* __restrict__ ad2) {
  __shared__ float wl[2][32][8];
  __shared__ float sv[256];
  __shared__ float zsh[2][8];
  __shared__ float sp[4][33];
  const int t = threadIdx.x;
  const int lane = t & 63;
  const int w = t >> 6;
  const int head = lane >> 3;
  const int n0 = blockIdx.x * 2;
  const int o0 = offs[n0], o1 = offs[n0 + 1], o2 = offs[n0 + 2];
  const uint2* h1u2 = (const uint2*)h1b;

  // prefetch chunk 0 of both nodes (index chain overlapped)
  int sreg[2] = {0, 0};
  const int cnt0 = min(32, o1 - o0);
  const int cnt1 = min(32, o2 - o1);
  if (lane < cnt0) sreg[0] = esrc[o0 + lane];
  if (lane < cnt1) sreg[1] = esrc[o1 + lane];
  {
    const int j = t >> 2, hh = (t & 3) * 2;
    if (j < cnt0) *(float2*)&wl[0][j][hh] = *(const float2*)(wt + (size_t)(o0 + j) * 8 + hh);
    if (j < cnt1) *(float2*)&wl[1][j][hh] = *(const float2*)(wt + (size_t)(o1 + j) * 8 + hh);
  }
  __syncthreads();

  for (int ns = 0; ns < 2; ++ns) {
    const int n = n0 + ns;
    const int sBeg = ns ? o1 : o0;
    const int sEnd = ns ? o2 : o1;
    float acc0 = 0.f, acc1 = 0.f, acc2 = 0.f, acc3 = 0.f, z = 0.f;
    if (w == 0) {   // self loop on wave 0
      float w0 = __expf(lrelu(as1[n * 8 + head] + ad1[n * 8 + head]));
      z = w0;
      uint2 q = h1u2[(size_t)n * 64 + lane];
      float f0, f1, f2, f3; unpack2(q.x, f0, f1); unpack2(q.y, f2, f3);
      acc0 = w0 * f0; acc1 = w0 * f1; acc2 = w0 * f2; acc3 = w0 * f3;
    }
    int sregc = sreg[ns];
    for (int base = sBeg; base < sEnd; base += 32) {
      const int cnt = min(32, sEnd - base);
      if (base != sBeg) {   // rare multi-chunk path: reload indices + weights
        sregc = 0;
        if (lane < cnt) sregc = esrc[base + lane];
        __syncthreads();
        const int j = t >> 2, hh = (t & 3) * 2;
        if (j < cnt) *(float2*)&wl[ns][j][hh] = *(const float2*)(wt + (size_t)(base + j) * 8 + hh);
        __syncthreads();
      }
#pragma unroll 8
      for (int j2 = w; j2 < cnt; j2 += 2) {
        int sj = __builtin_amdgcn_readlane(sregc, j2);   // uniform -> SGPR base
        uint2 q = h1u2[(size_t)sj * 64 + lane];          // full 512B row per wave
        float wv = wl[ns][j2][head];
        float f0, f1, f2, f3; unpack2(q.x, f0, f1); unpack2(q.y, f2, f3);
        z += wv;
        acc0 += wv * f0; acc1 += wv * f1; acc2 += wv * f2; acc3 += wv * f3;
      }
    }

    __syncthreads();
    if (w == 0) {
      *(float4*)&sv[4 * lane] = make_float4(acc0, acc1, acc2, acc3);
      if ((lane & 7) == 0) zsh[0][head] = z;
    }
    __syncthreads();
    if (w == 1) {
      float4 p = *(float4*)&sv[4 * lane];
      p.x += acc0; p.y += acc1; p.z += acc2; p.w += acc3;
      *(float4*)&sv[4 * lane] = p;
      if ((lane & 7) == 0) zsh[1][head] = z;
    }
    __syncthreads();
    {  // out1 = sv/z + b1, ELU (thread t -> channels 2t, 2t+1)
      const int ho = t >> 4;
      const float zf = zsh[0][ho] + zsh[1][ho];
      const float zi = 1.0f / (zf + 1e-16f);
      float2 bb = *(const float2*)(b1 + 2 * t);
      float v0 = sv[2 * t] * zi + bb.x;
      float v1 = sv[2 * t + 1] * zi + bb.y;
      v0 = v0 > 0.f ? v0 : (__expf(v0) - 1.0f);
      v1 = v1 > 0.f ? v1 : (__expf(v1) - 1.0f);
      __syncthreads();
      sv[2 * t] = v0; sv[2 * t + 1] = v1;
    }
    __syncthreads();
    // GEMM2 row: 4 k-slices of 64, c = output channel
    const int c = t & 31, rr = t >> 5;
    const float* svp = sv + rr * 64;
    const float* w2p = W2 + rr * 64 * 32 + c;
    float p = 0.f;
#pragma unroll 16
    for (int kk = 0; kk < 64; ++kk) p += svp[kk] * w2p[kk * 32];
    sp[rr][c] = p;
    __syncthreads();
    if (t < 32) {
      float hv = sp[0][t] + sp[1][t] + sp[2][t] + sp[3][t];
      h2b[(size_t)n * 32 + t] = f2bf(hv);
      float ps = hv * att_src2[t];
      float pd = hv * att_dst2[t];
#pragma unroll
      for (int m = 16; m >= 1; m >>= 1) {
        ps += __shfl_xor(ps, m, 64);
        pd += __shfl_xor(pd, m, 64);
      }
      if (t == 0) { as2[n] = ps; ad2[n] = pd; }
    }
    __syncthreads();   // protect sv/zsh/sp before next node
  }
}

// ---------------- layer-2 edge weights, edge-parallel ----------------
__global__ void k_ew2(const int* __restrict__ esrc, const int* __restrict__ edst,
                      const float* __restrict__ as2, const float* __restrict__ ad2,
                      float* __restrict__ wt2) {
  int p = blockIdx.x * 256 + threadIdx.x;
  if (p < EE) wt2[p] = __expf(lrelu(as2[esrc[p]] + ad2[edst[p]]));
}

// ---------------- agg2: softmax-weighted sum -> dense h3 ----------------
__global__ __launch_bounds__(256) void k_agg2(const unsigned short* __restrict__ h2b,
                                              const float* __restrict__ as2,
                                              const float* __restrict__ ad2,
                                              const int* __restrict__ offs,
                                              const int* __restrict__ esrc,
                                              const float* __restrict__ wt2,
                                              const float* __restrict__ b2,
                                              float* __restrict__ h3) {
  const int t = threadIdx.x;
  const int g = t >> 5, c = t & 31;
  const int n = blockIdx.x * 8 + g;
  const int sbase = t & 32;
  const int start = offs[n], end = offs[n + 1];
  float w0 = __expf(lrelu(as2[n] + ad2[n]));
  float z = w0;
  float acc = w0 * bf2f(h2b[(size_t)n * 32 + c]);
  for (int base = start; base < end; base += 32) {
    const int cnt = min(32, end - base);
    int s_reg = 0; float w_reg = 0.f;
    if (c < cnt) {
      s_reg = esrc[base + c];       // independent loads, chain depth 2
      w_reg = wt2[base + c];
    }
#pragma unroll 8
    for (int j = 0; j < cnt; ++j) {
      int sj = __shfl(s_reg, sbase + j, 64);
      float wj = __shfl(w_reg, sbase + j, 64);
      z += wj;
      acc += wj * bf2f(h2b[(size_t)sj * 32 + c]);
    }
  }
  h3[(size_t)n * 32 + c] = acc / (z + 1e-16f) + b2[c];
}

// ---------------- pool + final linear (fused) ----------------
__global__ __launch_bounds__(256) void k_poolfin(const float* __restrict__ h3,
                                                 const int* __restrict__ batch,
                                                 const float* __restrict__ Wlin,
                                                 const float* __restrict__ blin,
                                                 float* __restrict__ out) {
  __shared__ int bounds[2];
  __shared__ float red[8][33];
  __shared__ float mean[32];
  const int g = blockIdx.x;
  const int t = threadIdx.x;
  if (t < 2) {
    int target = g + t;
    int lo = 0, hi = NN;
    while (lo < hi) { int mid = (lo + hi) >> 1; if (batch[mid] < target) lo = mid + 1; else hi = mid; }
    bounds[t] = lo;
  }
  __syncthreads();
  const int lo = bounds[0], hi = bounds[1];
  const int rr = t >> 5, c = t & 31;
  float a = 0.f;
  for (int r = lo + rr; r < hi; r += 8) a += h3[(size_t)r * 32 + c];
  red[rr][c] = a;
  __syncthreads();
  if (rr == 0) {
    float s = 0.f;
#pragma unroll
    for (int i = 0; i < 8; ++i) s += red[i][c];
    float ct = (float)(hi - lo);
    ct = ct > 1.f ? ct : 1.f;
    mean[c] = s / ct;
  }
  __syncthreads();
  if (t < NC) {
    float acc = 0.f;
#pragma unroll
    for (int cc = 0; cc < 32; ++cc) acc += mean[cc] * Wlin[cc * NC + t];
    out[g * NC + t] = acc + blin[t];
  }
}

extern "C" void kernel_launch(void* const* d_in, const int* in_sizes, int n_in,
                              void* d_out, int out_size, void* d_ws, size_t ws_size,
                              hipStream_t stream) {
  const float* x        = (const float*)d_in[0];
  const int*   ei       = (const int*)d_in[1];
  const int*   batch    = (const int*)d_in[2];
  const float* W1       = (const float*)d_in[3];
  const float* att_src1 = (const float*)d_in[4];
  const float* att_dst1 = (const float*)d_in[5];
  const float* b1       = (const float*)d_in[6];
  const float* W2       = (const float*)d_in[7];
  const float* att_src2 = (const float*)d_in[8];
  const float* att_dst2 = (const float*)d_in[9];
  const float* b2       = (const float*)d_in[10];
  const float* Wlin     = (const float*)d_in[11];
  const float* blin     = (const float*)d_in[12];
  float* out = (float*)d_out;
  char* ws = (char*)d_ws;

  // workspace layout (bytes); peak ~130 MB (wt dead after agg1 -> wt2/h3 overlay)
  unsigned short* h1b = (unsigned short*)(ws + 0);        // 51,200,000
  float* as1   = (float*)(ws + 51200000);                 // 3,200,000
  float* ad1   = (float*)(ws + 54400000);                 // 3,200,000
  int* counts  = (int*)(ws + 57600000);                   // 400,000
  int* offs    = (int*)(ws + 58000000);                   // 400,004 (+pad)
  int* cursor  = (int*)(ws + 58400256);                   // 400,000
  int* esrc    = (int*)(ws + 58800256);                   // 6,400,000
  int* edst    = (int*)(ws + 65200256);                   // 6,400,000
  int* bsums   = (int*)(ws + 71600256);                   // 1,564 (+pad)
  unsigned short* h2b = (unsigned short*)(ws + 71602048); // 6,400,000
  float* as2   = (float*)(ws + 78002048);                 // 400,000
  float* ad2   = (float*)(ws + 78402048);                 // 400,000
  float* wt    = (float*)(ws + 78802048);                 // 51,200,000 (dead after agg1)
  float* wt2   = (float*)(ws + 78802048);                 // 6,400,000 (overlay)
  float* h3    = (float*)(ws + 85202048);                 // 12,800,000 (overlay)

  const int nb_scan = (NN + 255) / 256;  // 391

  k_zero<<<nb_scan, 256, 0, stream>>>((unsigned int*)counts, NN);

  dim3 g1((NN + 63) / 64, 2);
  k_gemm1<<<g1, 256, 0, stream>>>(x, W1, att_src1, att_dst1, h1b, as1, ad1);

  k_count<<<(EE + 255) / 256, 256, 0, stream>>>(ei, counts);
  k_scan1<<<nb_scan, 256, 0, stream>>>(counts, offs, bsums);
  k_scan2<<<1, 512, 0, stream>>>(bsums, nb_scan);
  k_scan3<<<nb_scan, 256, 0, stream>>>(offs, bsums, cursor);
  k_scatter<<<(EE + 255) / 256, 256, 0, stream>>>(ei, cursor, as1, ad1, esrc, edst, wt);

  k_agg1<<<NN / 2, 128, 0, stream>>>(h1b, as1, ad1, offs, esrc, wt, b1, W2,
                                     att_src2, att_dst2, h2b, as2, ad2);

  k_ew2<<<(EE + 255) / 256, 256, 0, stream>>>(esrc, edst, as2, ad2, wt2);
  k_agg2<<<NN / 8, 256, 0, stream>>>(h2b, as2, ad2, offs, esrc, wt2, b2, h3);
  k_poolfin<<<GG, 256, 0, stream>>>(h3, batch, Wlin, blin, out);
}